// Round 13
// baseline (551.158 us; speedup 1.0000x reference)
//
#include <hip/hip_runtime.h>
#include <math.h>
#include <float.h>

#define B_ 32
#define N_ 4097
#define C_ 256
#define F_ 2049
#define N2_ 241
#define Q_ 512                        // padded K (q = 2*n2 + p, zeros q>=482)
#define TWROWS 4352                   // stageC twiddle rows (m1-tail padded)
#define INV_SQRT_N 0.0156230927f      // 1/sqrt(4097)
#define W_N 0.0015336063f             // 2*pi/4097
#define W_17 0.36959913571644626f     // 2*pi/17

typedef __attribute__((ext_vector_type(8))) short short8v;
typedef _Float16 f16x8 __attribute__((ext_vector_type(8)));
typedef __attribute__((ext_vector_type(4))) float f32x4;

// 17-point DFT twiddles as compile-time literals (cos/sin(2*pi*r/17)).
#define C17T(r) ((r)==0 ? 1.0f : (r)==1 ? 0.9324722294f : (r)==2 ? 0.7390089172f : \
    (r)==3 ? 0.4457383558f : (r)==4 ? 0.0922683595f : (r)==5 ? -0.2736629901f : \
    (r)==6 ? -0.6026346364f : (r)==7 ? -0.8502171357f : (r)==8 ? -0.9829730997f : \
    (r)==9 ? -0.9829730997f : (r)==10 ? -0.8502171357f : (r)==11 ? -0.6026346364f : \
    (r)==12 ? -0.2736629901f : (r)==13 ? 0.0922683595f : (r)==14 ? 0.4457383558f : \
    (r)==15 ? 0.7390089172f : 0.9324722294f)
#define S17T(r) ((r)==0 ? 0.0f : (r)==1 ? 0.3612416662f : (r)==2 ? 0.6736956436f : \
    (r)==3 ? 0.8951632914f : (r)==4 ? 0.9957341763f : (r)==5 ? 0.9618256432f : \
    (r)==6 ? 0.7980172273f : (r)==7 ? 0.5264321629f : (r)==8 ? 0.1837495178f : \
    (r)==9 ? -0.1837495178f : (r)==10 ? -0.5264321629f : (r)==11 ? -0.7980172273f : \
    (r)==12 ? -0.9618256432f : (r)==13 ? -0.9957341763f : (r)==14 ? -0.8951632914f : \
    (r)==15 ? -0.6736956436f : -0.3612416662f)

__device__ __forceinline__ float bf2f(unsigned short u) {
    return __uint_as_float(((unsigned)u) << 16);
}
__device__ __forceinline__ unsigned short f2bf(float v) {
    unsigned u = __float_as_uint(v);
    u += 0x7FFFu + ((u >> 16) & 1u);
    return (unsigned short)(u >> 16);
}
__device__ __forceinline__ unsigned short f2h(float v) {
    union { _Float16 h; unsigned short u; } cv;
    cv.h = (_Float16)v;               // v_cvt_f16_f32, RTN
    return cv.u;
}
__device__ __forceinline__ void gload16(const void* gptr, void* ldsptr) {
    __builtin_amdgcn_global_load_lds(
        (const __attribute__((address_space(1))) void*)gptr,
        (__attribute__((address_space(3))) void*)ldsptr,
        16, 0, 0);
}

// ---------------------------------------------------------------------------
// k_prep: fused Stage A + twiddle fills.
//  blocks [0,2048): 17-point real DFT + transpose -> y_t fp16 [b][j][c][q];
//  blocks [2048,4224): fill twA (bf16, stageC) and twB (fp16, stageB).
//  launch_bounds(256,6): LDS 26KB x 6 blocks/CU = 156KB (occupancy lever).
// ---------------------------------------------------------------------------
__global__ __launch_bounds__(256, 6) void k_prep(const float* __restrict__ x,
                                                 unsigned short* __restrict__ yt,
                                                 unsigned short* __restrict__ twA,
                                                 unsigned short* __restrict__ twB) {
    int blk = blockIdx.x;
    int tid = threadIdx.x;
    if (blk >= 2048) {
        int base = (blk - 2048) * 4;
#pragma unroll
        for (int u = 0; u < 4; ++u) {
            int g = base + u;
            if (g < TWROWS) {
                int n = g, k2 = tid;
                unsigned pack = 0u;
                if (n <= 4096 && k2 <= 240) {
                    int rr = (n * k2) % N_;
                    float s, cth; sincosf(W_N * (float)rr, &s, &cth);
                    pack = (unsigned)f2bf(cth) | ((unsigned)f2bf(-s) << 16);
                }
                *(unsigned*)(twA + (size_t)n * Q_ + 2 * k2) = pack;
            } else {
                int i2 = g - TWROWS;         // 0..4351
                int m = i2 & 255; int k1 = i2 >> 8;
                int n2 = tid;
                int t = m >> 1, r = m & 1;
                int f = k1 + 17 * t;
                unsigned ph = 0u;
                if (t <= 120 && f < F_ && n2 <= 240) {
                    float s_ = (k1 <= 8) ? 1.f : -1.f;
                    int rr = (f * n2) % N_;
                    float sn, cs; sincosf(W_N * (float)rr, &sn, &cs);
                    float a0 = (r == 0) ? cs : -sn;
                    float a1 = (r == 0) ? s_ * sn : s_ * cs;
                    ph = (unsigned)f2h(a0) | ((unsigned)f2h(a1) << 16);
                }
                size_t ub = ((size_t)(k1 * 256 + m)) * 256 + n2;
                *((unsigned*)twB + ub) = ph;
            }
        }
        return;
    }

    // ---- stage A path: 16 n2-rows per block ----
    int b = blk >> 6; int rem = blk & 63;
    int n2t = rem >> 2, ct = rem & 3;
    int cl = tid & 63, sub = tid >> 6;
    int c = ct * 64 + cl;

    float ar[9][4], ai[8][4];
#pragma unroll
    for (int k = 0; k < 9; ++k)
#pragma unroll
        for (int i = 0; i < 4; ++i) ar[k][i] = 0.f;
#pragma unroll
    for (int k = 0; k < 8; ++k)
#pragma unroll
        for (int i = 0; i < 4; ++i) ai[k][i] = 0.f;

    const float* xb = x + (size_t)b * N_ * C_ + c;
#pragma unroll
    for (int n1 = 0; n1 < 17; ++n1) {
        float xv[4];
#pragma unroll
        for (int i = 0; i < 4; ++i) {
            int n2 = n2t * 16 + sub * 4 + i;
            xv[i] = (n2 <= 240) ? xb[(size_t)(n1 * N2_ + n2) * C_] : 0.f;
        }
#pragma unroll
        for (int k1 = 0; k1 < 9; ++k1) {
            const int r = (k1 * n1) % 17;     // compile-time after unroll
            const float cc = C17T(r), ss = S17T(r);
#pragma unroll
            for (int i = 0; i < 4; ++i) {
                ar[k1][i] += xv[i] * cc;
                if (k1 > 0) ai[k1 - 1][i] += xv[i] * ss;
            }
        }
    }

    __shared__ float lre[3 * 16 * 68], lim[3 * 16 * 68];   // 26 KB
    int c2 = tid >> 2, qg = tid & 3;
#pragma unroll
    for (int g = 0; g < 3; ++g) {
        __syncthreads();                  // protect previous round's reads
#pragma unroll
        for (int jj = 0; jj < 3; ++jj) {
            int j = g * 3 + jj;
#pragma unroll
            for (int i = 0; i < 4; ++i) {
                int row = sub * 4 + i;
                lre[(jj * 16 + row) * 68 + cl] = ar[j][i] * INV_SQRT_N;
                lim[(jj * 16 + row) * 68 + cl] = (j > 0) ? (-ai[j - 1][i] * INV_SQRT_N) : 0.f;
            }
        }
        __syncthreads();
#pragma unroll
        for (int jj = 0; jj < 3; ++jj) {
            int j = g * 3 + jj;
            unsigned wh[4];
#pragma unroll
            for (int i = 0; i < 4; ++i) {
                int row = qg * 4 + i;
                float re = lre[(jj * 16 + row) * 68 + c2];
                float im = lim[(jj * 16 + row) * 68 + c2];
                wh[i] = (unsigned)f2h(re) | ((unsigned)f2h(im) << 16);
            }
            size_t ubase = ((size_t)((b * 9 + j) * 256 + ct * 64 + c2)) * 256 + n2t * 16 + qg * 4;
            uint4 v0; v0.x = wh[0]; v0.y = wh[1]; v0.z = wh[2]; v0.w = wh[3];
            *(uint4*)((unsigned*)yt + ubase) = v0;
        }
    }
}

// ---------------------------------------------------------------------------
// Stage B v6: double-buffered fp16 MFMA GEMM + LDS-transposed coalesced
// epilogue + atomic-free energy.  launch_bounds(256,4): 4 blocks/CU.
// grid 2176 = B*68, chunk-swizzled.
// ---------------------------------------------------------------------------
__global__ __launch_bounds__(256, 4) void k_stageB_v6(
        const unsigned short* __restrict__ yt, const unsigned short* __restrict__ twb,
        unsigned short* __restrict__ X, float* __restrict__ e2) {
    int bid = (blockIdx.x & 7) * 272 + (blockIdx.x >> 3);   // 2176 = 8*272
    int b = bid / 68, rem = bid % 68;
    int j, mt, ct;
    if (rem < 4) { j = 0; mt = rem >> 1; ct = rem & 1; }
    else { int r2 = rem - 4; j = 1 + (r2 >> 3); int sub = r2 & 7; mt = sub >> 1; ct = sub & 1; }
    int k1 = (mt < 2) ? j : 17 - j;
    int mh = mt & 1;
    const unsigned short* pA = twb + (size_t)(k1 * 256 + mh * 128) * Q_;
    const unsigned short* pB = yt + (size_t)((b * 9 + j) * 256 + ct * 128) * Q_;

    int tid = threadIdx.x, lane = tid & 63, wid = tid >> 6;
    int wr = wid >> 1, wc = wid & 1;
    int l15 = lane & 15, lg = lane >> 4;
    int srow = lane >> 2, sch = lane & 3;      // staging: 16 rows x 4 chunks of 16B

    __shared__ __align__(16) unsigned short lds[2][8192];  // A[128][32] | B[128][32]
    __shared__ float eL[2][2][4][4][2];

    const unsigned short* gsrc[4];
#pragma unroll
    for (int r = 0; r < 4; ++r) {
        int row = (r & 1) * 64 + wid * 16 + srow;
        int ch = sch ^ ((row >> 1) & 3);
        gsrc[r] = ((r < 2) ? pA : pB) + (size_t)row * Q_ + ch * 8;
    }
    int aoff[4], boff[4];
#pragma unroll
    for (int rt = 0; rt < 4; ++rt) {
        int row = wr * 64 + rt * 16 + l15;
        aoff[rt] = row * 32 + (lg ^ ((row >> 1) & 3)) * 8;
    }
#pragma unroll
    for (int nt = 0; nt < 4; ++nt) {
        int row = wc * 64 + nt * 16 + l15;
        boff[nt] = 4096 + row * 32 + (lg ^ ((row >> 1) & 3)) * 8;
    }

    f32x4 acc[4][4];
#pragma unroll
    for (int rt = 0; rt < 4; ++rt)
#pragma unroll
        for (int nt = 0; nt < 4; ++nt) acc[rt][nt] = (f32x4){0.f, 0.f, 0.f, 0.f};

#define STAGE_B(bufi, q0) do {                                      \
        gload16(gsrc[0] + (q0), &lds[bufi][wid * 512]);             \
        gload16(gsrc[1] + (q0), &lds[bufi][2048 + wid * 512]);      \
        gload16(gsrc[2] + (q0), &lds[bufi][4096 + wid * 512]);      \
        gload16(gsrc[3] + (q0), &lds[bufi][6144 + wid * 512]);      \
    } while (0)

#define COMP_B(bufi) do {                                           \
        f16x8 a_[4], b_[4];                                         \
        _Pragma("unroll")                                           \
        for (int rt = 0; rt < 4; ++rt)                              \
            a_[rt] = *(const f16x8*)&lds[bufi][aoff[rt]];           \
        _Pragma("unroll")                                           \
        for (int nt = 0; nt < 4; ++nt)                              \
            b_[nt] = *(const f16x8*)&lds[bufi][boff[nt]];           \
        _Pragma("unroll")                                           \
        for (int rt = 0; rt < 4; ++rt)                              \
            _Pragma("unroll")                                       \
            for (int nt = 0; nt < 4; ++nt)                          \
                acc[rt][nt] = __builtin_amdgcn_mfma_f32_16x16x32_f16( \
                    a_[rt], b_[nt], acc[rt][nt], 0, 0, 0);          \
    } while (0)

    STAGE_B(0, 0);
    __syncthreads();
    for (int ks = 0; ks < 16; ks += 2) {
        STAGE_B(1, (ks + 1) * 32);
        COMP_B(0);
        __syncthreads();
        if (ks + 2 < 16) STAGE_B(0, (ks + 2) * 32);
        COMP_B(1);
        __syncthreads();
    }
#undef STAGE_B
#undef COMP_B

    // ---- energy: partial sum over this block's 128 c -> e2[ct] slot ----
#pragma unroll
    for (int rt = 0; rt < 4; ++rt) {
        float e0 = 0.f, e1 = 0.f;
#pragma unroll
        for (int nt = 0; nt < 4; ++nt) {
            e0 += acc[rt][nt][0] * acc[rt][nt][0] + acc[rt][nt][1] * acc[rt][nt][1];
            e1 += acc[rt][nt][2] * acc[rt][nt][2] + acc[rt][nt][3] * acc[rt][nt][3];
        }
#pragma unroll
        for (int off = 1; off < 16; off <<= 1) {
            e0 += __shfl_xor(e0, off, 64);
            e1 += __shfl_xor(e1, off, 64);
        }
        if (l15 == 0) { eL[wr][wc][rt][lg][0] = e0; eL[wr][wc][rt][lg][1] = e1; }
    }
    __syncthreads();
    if (tid < 64) {
        int wr2 = tid >> 5, rt2 = (tid >> 3) & 3, lg2 = (tid >> 1) & 3, pr = tid & 1;
        int mrow = mh * 128 + wr2 * 64 + rt2 * 16 + lg2 * 4 + pr * 2;
        int f = k1 + 17 * (mrow >> 1);
        if (f < F_) {
            float e = eL[wr2][0][rt2][lg2][pr] + eL[wr2][1][rt2][lg2][pr];
            e2[(size_t)ct * (B_ * F_) + b * F_ + f] = e;
        }
    }

    // ---- X store via LDS transpose: one 256B contiguous u32-row per wave ----
    unsigned short* st = (unsigned short*)lds;     // [32][132] u16 per rt chunk
#pragma unroll
    for (int rt = 0; rt < 4; ++rt) {
        __syncthreads();
#pragma unroll
        for (int nt = 0; nt < 4; ++nt)
#pragma unroll
            for (int jj = 0; jj < 4; ++jj) {
                int ri = wr * 16 + lg * 4 + jj;
                int col = wc * 64 + nt * 16 + l15;
                st[ri * 132 + col] = f2bf(acc[rt][nt][jj]);
            }
        __syncthreads();
#pragma unroll
        for (int rr = 0; rr < 8; ++rr) {
            int ri = wid * 8 + rr;
            int mrow = mh * 128 + (ri >> 4) * 64 + rt * 16 + (ri & 15);
            int t = mrow >> 1, p = mrow & 1;
            int f = k1 + 17 * t;
            if (f < F_) {
                unsigned v = *(unsigned*)&st[ri * 132 + 2 * lane];
                *(unsigned*)(X + ((size_t)((b * F_ + f) * 2 + p)) * C_ + ct * 128 + 2 * lane) = v;
            }
        }
    }
}

// ---------------------------------------------------------------------------
// Median per batch via exact 4-pass radix select on summed energy halves.
// ---------------------------------------------------------------------------
__global__ __launch_bounds__(256) void k_median(const float* __restrict__ e2,
                                                float* __restrict__ med) {
    int b = blockIdx.x, tid = threadIdx.x;
    __shared__ unsigned vals[F_];
    __shared__ unsigned hist[256];
    __shared__ unsigned scanbuf[256];
    __shared__ unsigned sh_prefix;
    __shared__ int sh_rank;
    for (int i = tid; i < F_; i += 256)
        vals[i] = __float_as_uint(e2[b * F_ + i] + e2[(size_t)B_ * F_ + b * F_ + i]);
    if (tid == 0) { sh_prefix = 0u; sh_rank = 1024; }
    __syncthreads();
#pragma unroll
    for (int shift = 24; shift >= 0; shift -= 8) {
        hist[tid] = 0u;
        __syncthreads();
        unsigned prefix = sh_prefix;
        unsigned hmask = (shift == 24) ? 0u : (0xFFFFFFFFu << (shift + 8));
        for (int i = tid; i < F_; i += 256) {
            unsigned v = vals[i];
            if (((v ^ prefix) & hmask) == 0u)
                atomicAdd(&hist[(v >> shift) & 255], 1u);
        }
        __syncthreads();
        scanbuf[tid] = hist[tid];
        __syncthreads();
#pragma unroll
        for (int off = 1; off < 256; off <<= 1) {
            unsigned y = (tid >= off) ? scanbuf[tid - off] : 0u;
            __syncthreads();
            scanbuf[tid] += y;
            __syncthreads();
        }
        int rank = sh_rank;
        unsigned cumP = (tid == 0) ? 0u : scanbuf[tid - 1];
        unsigned cumI = scanbuf[tid];
        __syncthreads();
        if ((unsigned)rank >= cumP && (unsigned)rank < cumI) {
            sh_prefix = prefix | ((unsigned)tid << shift);
            sh_rank = rank - (int)cumP;
        }
        __syncthreads();
    }
    if (tid == 0) med[b] = __uint_as_float(sh_prefix);
}

// ---------------------------------------------------------------------------
// vbuild (tiled, 16-k2 tiles): mask + weights + inverse inner 17-point stage.
// launch_bounds(256,4): LDS 37KB x 4 = 148KB.
// ---------------------------------------------------------------------------
__global__ __launch_bounds__(256, 4) void k_vbuild_t(
        const unsigned short* __restrict__ X, const float* __restrict__ e2,
        const float* __restrict__ med, const float* __restrict__ thr,
        const float* __restrict__ cw, const float* __restrict__ cwh,
        unsigned short* __restrict__ vt) {
    int bid = blockIdx.x;            // 32*16*8 = 4096
    int b = bid >> 7; int rem = bid & 127;
    int kt = rem >> 3, ct = rem & 7;
    int tid = threadIdx.x;
    int cl = tid & 31, ks = tid >> 5;
    int c = ct * 32 + cl;

    __shared__ unsigned stage[17 * 32 * 17];   // [m2][cl][klocal(16) pad->17] ~37KB

    float wr = cw[2 * c], wi = cw[2 * c + 1];
    float whr = cwh[2 * c], whi = cwh[2 * c + 1];
    float denom = med[b] + 1e-6f;

#pragma unroll
    for (int kk = 0; kk < 2; ++kk) {
        int klocal = kk * 8 + ks;
        int k2 = kt * 16 + klocal;
        float vr[17], vi[17];
#pragma unroll
        for (int m = 0; m < 17; ++m) { vr[m] = 0.f; vi[m] = 0.f; }
        if (k2 <= 240) {
#pragma unroll
            for (int s = 0; s < 9; ++s) {
                int f = k2 + 241 * s;
                if (f < F_) {
                    float e = e2[b * F_ + f] + e2[(size_t)B_ * F_ + b * F_ + f];
                    float m = (e / denom > thr[f]) ? 1.0f : 0.0f;
                    float wer = wr + m * whr, wei = wi + m * whi;
                    float cf = ((f == 0) ? 1.0f : 2.0f) * INV_SQRT_N;
                    const unsigned short* Xrow = X + ((size_t)(b * F_ + f) * 2) * C_;
                    float Xr = bf2f(Xrow[c]), Xi = bf2f(Xrow[C_ + c]);
                    float Zr = (Xr * wer - Xi * wei) * cf;
                    float Zi = (Xr * wei + Xi * wer) * cf;
#pragma unroll
                    for (int m2 = 0; m2 < 17; ++m2) {
                        const int r = (s * m2) % 17;
                        vr[m2] += Zr * C17T(r) - Zi * S17T(r);
                        vi[m2] += Zr * S17T(r) + Zi * C17T(r);
                    }
                }
            }
        }
#pragma unroll
        for (int m2 = 0; m2 < 17; ++m2)
            stage[(m2 * 32 + cl) * 17 + klocal] =
                (unsigned)f2bf(vr[m2]) | ((unsigned)f2bf(vi[m2]) << 16);
    }
    __syncthreads();
    unsigned* vt32 = (unsigned*)vt;
    for (int r = tid; r < 544; r += 256) {
        int m2 = r >> 5, c2 = r & 31;
        size_t ubase = ((size_t)((b * 17 + m2) * 256 + ct * 32 + c2)) * 256 + kt * 16;
        const unsigned* srow = &stage[(m2 * 32 + c2) * 17];
#pragma unroll
        for (int g = 0; g < 4; ++g) {
            uint4 w;
            w.x = srow[g * 4]; w.y = srow[g * 4 + 1];
            w.z = srow[g * 4 + 2]; w.w = srow[g * 4 + 3];
            *(uint4*)(vt32 + ubase + g * 4) = w;
        }
    }
}

// ---------------------------------------------------------------------------
// Stage C v5: double-buffered bf16 MFMA GEMM, N=256 per block (A staged once,
// 32 MFMA per 12 ds_read), LDS-transposed epilogue with full-1KB row stores.
// launch_bounds(256,3): 48KB x 3 = 144KB -> 3 blocks/CU.
// grid 1088 = B*34 (m2 x mt), chunk-swizzled; 4 waves 2Mx2N; acc[4][8].
// ---------------------------------------------------------------------------
__global__ __launch_bounds__(256, 3) void k_stageC_v5(const short* __restrict__ vt,
                                                      const short* __restrict__ twA,
                                                      float* __restrict__ out) {
    int bid = (blockIdx.x & 7) * 136 + (blockIdx.x >> 3);   // 1088 = 8*136
    int b = bid / 34, rem = bid % 34;
    int m2 = rem >> 1, mt = rem & 1;

    int tid = threadIdx.x, lane = tid & 63, wid = tid >> 6;
    int wr = wid >> 1, wc = wid & 1;
    int l15 = lane & 15, lg = lane >> 4;
    int srow = lane >> 2, sch = lane & 3;      // staging: 16 rows x 4 chunks of 16B

    const short* vtb = vt + (size_t)((b * 17 + m2) * 256) * Q_;

    // per buffer: A [128][32] (4096 sh) | B [256][32] (8192 sh) = 24 KB
    __shared__ __align__(16) short lds[2][12288];

    const short* gsrc[6];
#pragma unroll
    for (int r = 0; r < 6; ++r) {
        if (r < 2) {
            int row = r * 64 + wid * 16 + srow;            // 0..127
            int ch = sch ^ ((row >> 1) & 3);
            int n = 17 * (mt * 128 + row) + m2;
            gsrc[r] = twA + (size_t)n * Q_ + ch * 8;
        } else {
            int row = (r - 2) * 64 + wid * 16 + srow;      // 0..255
            int ch = sch ^ ((row >> 1) & 3);
            gsrc[r] = vtb + (size_t)row * Q_ + ch * 8;
        }
    }
    int aoff[4], boff[8];
#pragma unroll
    for (int rt = 0; rt < 4; ++rt) {
        int row = wr * 64 + rt * 16 + l15;
        aoff[rt] = row * 32 + (lg ^ ((row >> 1) & 3)) * 8;
    }
#pragma unroll
    for (int nt = 0; nt < 8; ++nt) {
        int row = wc * 128 + nt * 16 + l15;
        boff[nt] = 4096 + row * 32 + (lg ^ ((row >> 1) & 3)) * 8;
    }

    f32x4 acc[4][8];
#pragma unroll
    for (int rt = 0; rt < 4; ++rt)
#pragma unroll
        for (int nt = 0; nt < 8; ++nt) acc[rt][nt] = (f32x4){0.f, 0.f, 0.f, 0.f};

#define STAGE_C(bufi, q0) do {                                      \
        gload16(gsrc[0] + (q0), &lds[bufi][wid * 512]);             \
        gload16(gsrc[1] + (q0), &lds[bufi][2048 + wid * 512]);      \
        gload16(gsrc[2] + (q0), &lds[bufi][4096 + wid * 512]);      \
        gload16(gsrc[3] + (q0), &lds[bufi][6144 + wid * 512]);      \
        gload16(gsrc[4] + (q0), &lds[bufi][8192 + wid * 512]);      \
        gload16(gsrc[5] + (q0), &lds[bufi][10240 + wid * 512]);     \
    } while (0)

#define COMP_C(bufi) do {                                           \
        short8v a_[4], b_[8];                                       \
        _Pragma("unroll")                                           \
        for (int rt = 0; rt < 4; ++rt)                              \
            a_[rt] = *(const short8v*)&lds[bufi][aoff[rt]];         \
        _Pragma("unroll")                                           \
        for (int nt = 0; nt < 8; ++nt)                              \
            b_[nt] = *(const short8v*)&lds[bufi][boff[nt]];         \
        _Pragma("unroll")                                           \
        for (int rt = 0; rt < 4; ++rt)                              \
            _Pragma("unroll")                                       \
            for (int nt = 0; nt < 8; ++nt)                          \
                acc[rt][nt] = __builtin_amdgcn_mfma_f32_16x16x32_bf16( \
                    a_[rt], b_[nt], acc[rt][nt], 0, 0, 0);          \
    } while (0)

    STAGE_C(0, 0);
    __syncthreads();
    for (int ks = 0; ks < 16; ks += 2) {
        STAGE_C(1, (ks + 1) * 32);
        COMP_C(0);
        __syncthreads();
        if (ks + 2 < 16) STAGE_C(0, (ks + 2) * 32);
        COMP_C(1);
        __syncthreads();
    }
#undef STAGE_C
#undef COMP_C

    // ---- epilogue: LDS transpose -> one contiguous 1KB float4-row per wave --
    float* fl = (float*)lds;                   // [32][260] f32 per rt chunk (33 KB)
#pragma unroll
    for (int rt = 0; rt < 4; ++rt) {
        __syncthreads();
#pragma unroll
        for (int nt = 0; nt < 8; ++nt)
#pragma unroll
            for (int jj = 0; jj < 4; ++jj) {
                int ri = wr * 16 + lg * 4 + jj;
                int col = wc * 128 + nt * 16 + l15;
                fl[ri * 260 + col] = acc[rt][nt][jj];
            }
        __syncthreads();
#pragma unroll
        for (int rr = 0; rr < 8; ++rr) {
            int ri = wid * 8 + rr;
            int m1 = mt * 128 + (ri >> 4) * 64 + rt * 16 + (ri & 15);
            if (m1 < N2_) {
                int n = 17 * m1 + m2;
                float4 v = *(float4*)&fl[ri * 260 + 4 * lane];
                *(float4*)(out + ((size_t)b * N_ + n) * C_ + 4 * lane) = v;
            }
        }
    }
}

// ---------------------------------------------------------------------------
extern "C" void kernel_launch(void* const* d_in, const int* in_sizes, int n_in,
                              void* d_out, int out_size, void* d_ws, size_t ws_size,
                              hipStream_t stream) {
    const float* x   = (const float*)d_in[0];
    const float* cw  = (const float*)d_in[1];
    const float* cwh = (const float*)d_in[2];
    const float* thr = (const float*)d_in[3];
    float* out = (float*)d_out;

    // workspace (~219 MB), v_t aliases the dead y_t region:
    //   X     bf16 [B][F][2][C]          :  67,141,632
    //   SH    region (y_t | v_t):
    //     y_t  fp16 [B][9][256][512]     :  75,497,472
    //     v_t  bf16 [B][17][256][512]    : 142,606,336 (aliased at SH base)
    //   twA   bf16 [4352][512]           :   4,456,448
    //   twB   fp16 [17][256][512]        :   4,456,448
    //   e2    f32 [2][B][F]              :     524,544
    //   med   f32 [B]                    :         128
    char* ws = (char*)d_ws;
    unsigned short* Xb    = (unsigned short*)ws;
    char* sh = ws + 67141632ull;
    unsigned short* yt    = (unsigned short*)sh;
    unsigned short* vtb   = (unsigned short*)sh;                 // alias
    char* tail = sh + 142606336ull;
    unsigned short* twA   = (unsigned short*)tail;
    unsigned short* twB   = (unsigned short*)(tail + 4456448ull);
    float* e2  = (float*)(tail + 8912896ull);
    float* med = (float*)(tail + 8912896ull + 524544ull);

    k_prep<<<4224, 256, 0, stream>>>(x, yt, twA, twB);
    k_stageB_v6<<<B_ * 68, 256, 0, stream>>>(yt, twB, Xb, e2);
    k_median<<<B_, 256, 0, stream>>>(e2, med);
    k_vbuild_t<<<B_ * 128, 256, 0, stream>>>(Xb, e2, med, thr, cw, cwh, vtb);
    k_stageC_v5<<<B_ * 34, 256, 0, stream>>>((const short*)vtb, (const short*)twA, out);
}

// Round 14
// 332.322 us; speedup vs baseline: 1.6585x; 1.6585x over previous
//
#include <hip/hip_runtime.h>
#include <math.h>
#include <float.h>

#define B_ 32
#define N_ 4097
#define C_ 256
#define F_ 2049
#define N2_ 241
#define Q_ 512                        // padded K (q = 2*n2 + p, zeros q>=482)
#define TWROWS 4352                   // stageC twiddle rows (m1-tail padded)
#define INV_SQRT_N 0.0156230927f      // 1/sqrt(4097)
#define W_N 0.0015336063f             // 2*pi/4097
#define W_17 0.36959913571644626f     // 2*pi/17

typedef __attribute__((ext_vector_type(8))) short short8v;
typedef _Float16 f16x8 __attribute__((ext_vector_type(8)));
typedef __attribute__((ext_vector_type(4))) float f32x4;

// 17-point DFT twiddles as compile-time literals (cos/sin(2*pi*r/17)).
#define C17T(r) ((r)==0 ? 1.0f : (r)==1 ? 0.9324722294f : (r)==2 ? 0.7390089172f : \
    (r)==3 ? 0.4457383558f : (r)==4 ? 0.0922683595f : (r)==5 ? -0.2736629901f : \
    (r)==6 ? -0.6026346364f : (r)==7 ? -0.8502171357f : (r)==8 ? -0.9829730997f : \
    (r)==9 ? -0.9829730997f : (r)==10 ? -0.8502171357f : (r)==11 ? -0.6026346364f : \
    (r)==12 ? -0.2736629901f : (r)==13 ? 0.0922683595f : (r)==14 ? 0.4457383558f : \
    (r)==15 ? 0.7390089172f : 0.9324722294f)
#define S17T(r) ((r)==0 ? 0.0f : (r)==1 ? 0.3612416662f : (r)==2 ? 0.6736956436f : \
    (r)==3 ? 0.8951632914f : (r)==4 ? 0.9957341763f : (r)==5 ? 0.9618256432f : \
    (r)==6 ? 0.7980172273f : (r)==7 ? 0.5264321629f : (r)==8 ? 0.1837495178f : \
    (r)==9 ? -0.1837495178f : (r)==10 ? -0.5264321629f : (r)==11 ? -0.7980172273f : \
    (r)==12 ? -0.9618256432f : (r)==13 ? -0.9957341763f : (r)==14 ? -0.8951632914f : \
    (r)==15 ? -0.6736956436f : -0.3612416662f)

__device__ __forceinline__ float bf2f(unsigned short u) {
    return __uint_as_float(((unsigned)u) << 16);
}
__device__ __forceinline__ unsigned short f2bf(float v) {
    unsigned u = __float_as_uint(v);
    u += 0x7FFFu + ((u >> 16) & 1u);
    return (unsigned short)(u >> 16);
}
__device__ __forceinline__ unsigned short f2h(float v) {
    union { _Float16 h; unsigned short u; } cv;
    cv.h = (_Float16)v;               // v_cvt_f16_f32, RTN
    return cv.u;
}
__device__ __forceinline__ void gload16(const void* gptr, void* ldsptr) {
    __builtin_amdgcn_global_load_lds(
        (const __attribute__((address_space(1))) void*)gptr,
        (__attribute__((address_space(3))) void*)ldsptr,
        16, 0, 0);
}

// ---------------------------------------------------------------------------
// k_prep: fused Stage A + twiddle fills.
//  blocks [0,2048): 17-point real DFT + transpose -> y_t fp16 [b][j][c][q];
//  blocks [2048,4224): fill twA (bf16, stageC) and twB (fp16, stageB).
//  launch_bounds(256,6): LDS 26KB x 6 blocks/CU; VGPR 64 <= 85 budget (no spill).
// ---------------------------------------------------------------------------
__global__ __launch_bounds__(256, 6) void k_prep(const float* __restrict__ x,
                                                 unsigned short* __restrict__ yt,
                                                 unsigned short* __restrict__ twA,
                                                 unsigned short* __restrict__ twB) {
    int blk = blockIdx.x;
    int tid = threadIdx.x;
    if (blk >= 2048) {
        int base = (blk - 2048) * 4;
#pragma unroll
        for (int u = 0; u < 4; ++u) {
            int g = base + u;
            if (g < TWROWS) {
                int n = g, k2 = tid;
                unsigned pack = 0u;
                if (n <= 4096 && k2 <= 240) {
                    int rr = (n * k2) % N_;
                    float s, cth; sincosf(W_N * (float)rr, &s, &cth);
                    pack = (unsigned)f2bf(cth) | ((unsigned)f2bf(-s) << 16);
                }
                *(unsigned*)(twA + (size_t)n * Q_ + 2 * k2) = pack;
            } else {
                int i2 = g - TWROWS;         // 0..4351
                int m = i2 & 255; int k1 = i2 >> 8;
                int n2 = tid;
                int t = m >> 1, r = m & 1;
                int f = k1 + 17 * t;
                unsigned ph = 0u;
                if (t <= 120 && f < F_ && n2 <= 240) {
                    float s_ = (k1 <= 8) ? 1.f : -1.f;
                    int rr = (f * n2) % N_;
                    float sn, cs; sincosf(W_N * (float)rr, &sn, &cs);
                    float a0 = (r == 0) ? cs : -sn;
                    float a1 = (r == 0) ? s_ * sn : s_ * cs;
                    ph = (unsigned)f2h(a0) | ((unsigned)f2h(a1) << 16);
                }
                size_t ub = ((size_t)(k1 * 256 + m)) * 256 + n2;
                *((unsigned*)twB + ub) = ph;
            }
        }
        return;
    }

    // ---- stage A path: 16 n2-rows per block ----
    int b = blk >> 6; int rem = blk & 63;
    int n2t = rem >> 2, ct = rem & 3;
    int cl = tid & 63, sub = tid >> 6;
    int c = ct * 64 + cl;

    float ar[9][4], ai[8][4];
#pragma unroll
    for (int k = 0; k < 9; ++k)
#pragma unroll
        for (int i = 0; i < 4; ++i) ar[k][i] = 0.f;
#pragma unroll
    for (int k = 0; k < 8; ++k)
#pragma unroll
        for (int i = 0; i < 4; ++i) ai[k][i] = 0.f;

    const float* xb = x + (size_t)b * N_ * C_ + c;
#pragma unroll
    for (int n1 = 0; n1 < 17; ++n1) {
        float xv[4];
#pragma unroll
        for (int i = 0; i < 4; ++i) {
            int n2 = n2t * 16 + sub * 4 + i;
            xv[i] = (n2 <= 240) ? xb[(size_t)(n1 * N2_ + n2) * C_] : 0.f;
        }
#pragma unroll
        for (int k1 = 0; k1 < 9; ++k1) {
            const int r = (k1 * n1) % 17;     // compile-time after unroll
            const float cc = C17T(r), ss = S17T(r);
#pragma unroll
            for (int i = 0; i < 4; ++i) {
                ar[k1][i] += xv[i] * cc;
                if (k1 > 0) ai[k1 - 1][i] += xv[i] * ss;
            }
        }
    }

    __shared__ float lre[3 * 16 * 68], lim[3 * 16 * 68];   // 26 KB
    int c2 = tid >> 2, qg = tid & 3;
#pragma unroll
    for (int g = 0; g < 3; ++g) {
        __syncthreads();                  // protect previous round's reads
#pragma unroll
        for (int jj = 0; jj < 3; ++jj) {
            int j = g * 3 + jj;
#pragma unroll
            for (int i = 0; i < 4; ++i) {
                int row = sub * 4 + i;
                lre[(jj * 16 + row) * 68 + cl] = ar[j][i] * INV_SQRT_N;
                lim[(jj * 16 + row) * 68 + cl] = (j > 0) ? (-ai[j - 1][i] * INV_SQRT_N) : 0.f;
            }
        }
        __syncthreads();
#pragma unroll
        for (int jj = 0; jj < 3; ++jj) {
            int j = g * 3 + jj;
            unsigned wh[4];
#pragma unroll
            for (int i = 0; i < 4; ++i) {
                int row = qg * 4 + i;
                float re = lre[(jj * 16 + row) * 68 + c2];
                float im = lim[(jj * 16 + row) * 68 + c2];
                wh[i] = (unsigned)f2h(re) | ((unsigned)f2h(im) << 16);
            }
            size_t ubase = ((size_t)((b * 9 + j) * 256 + ct * 64 + c2)) * 256 + n2t * 16 + qg * 4;
            uint4 v0; v0.x = wh[0]; v0.y = wh[1]; v0.z = wh[2]; v0.w = wh[3];
            *(uint4*)((unsigned*)yt + ubase) = v0;
        }
    }
}

// ---------------------------------------------------------------------------
// Stage B v6: double-buffered fp16 MFMA GEMM + LDS-transposed coalesced
// epilogue + atomic-free energy.  launch_bounds(256,4): VGPR ~100 <= 128.
// grid 2176 = B*68, chunk-swizzled.
// ---------------------------------------------------------------------------
__global__ __launch_bounds__(256, 4) void k_stageB_v6(
        const unsigned short* __restrict__ yt, const unsigned short* __restrict__ twb,
        unsigned short* __restrict__ X, float* __restrict__ e2) {
    int bid = (blockIdx.x & 7) * 272 + (blockIdx.x >> 3);   // 2176 = 8*272
    int b = bid / 68, rem = bid % 68;
    int j, mt, ct;
    if (rem < 4) { j = 0; mt = rem >> 1; ct = rem & 1; }
    else { int r2 = rem - 4; j = 1 + (r2 >> 3); int sub = r2 & 7; mt = sub >> 1; ct = sub & 1; }
    int k1 = (mt < 2) ? j : 17 - j;
    int mh = mt & 1;
    const unsigned short* pA = twb + (size_t)(k1 * 256 + mh * 128) * Q_;
    const unsigned short* pB = yt + (size_t)((b * 9 + j) * 256 + ct * 128) * Q_;

    int tid = threadIdx.x, lane = tid & 63, wid = tid >> 6;
    int wr = wid >> 1, wc = wid & 1;
    int l15 = lane & 15, lg = lane >> 4;
    int srow = lane >> 2, sch = lane & 3;      // staging: 16 rows x 4 chunks of 16B

    __shared__ __align__(16) unsigned short lds[2][8192];  // A[128][32] | B[128][32]
    __shared__ float eL[2][2][4][4][2];

    const unsigned short* gsrc[4];
#pragma unroll
    for (int r = 0; r < 4; ++r) {
        int row = (r & 1) * 64 + wid * 16 + srow;
        int ch = sch ^ ((row >> 1) & 3);
        gsrc[r] = ((r < 2) ? pA : pB) + (size_t)row * Q_ + ch * 8;
    }
    int aoff[4], boff[4];
#pragma unroll
    for (int rt = 0; rt < 4; ++rt) {
        int row = wr * 64 + rt * 16 + l15;
        aoff[rt] = row * 32 + (lg ^ ((row >> 1) & 3)) * 8;
    }
#pragma unroll
    for (int nt = 0; nt < 4; ++nt) {
        int row = wc * 64 + nt * 16 + l15;
        boff[nt] = 4096 + row * 32 + (lg ^ ((row >> 1) & 3)) * 8;
    }

    f32x4 acc[4][4];
#pragma unroll
    for (int rt = 0; rt < 4; ++rt)
#pragma unroll
        for (int nt = 0; nt < 4; ++nt) acc[rt][nt] = (f32x4){0.f, 0.f, 0.f, 0.f};

#define STAGE_B(bufi, q0) do {                                      \
        gload16(gsrc[0] + (q0), &lds[bufi][wid * 512]);             \
        gload16(gsrc[1] + (q0), &lds[bufi][2048 + wid * 512]);      \
        gload16(gsrc[2] + (q0), &lds[bufi][4096 + wid * 512]);      \
        gload16(gsrc[3] + (q0), &lds[bufi][6144 + wid * 512]);      \
    } while (0)

#define COMP_B(bufi) do {                                           \
        f16x8 a_[4], b_[4];                                         \
        _Pragma("unroll")                                           \
        for (int rt = 0; rt < 4; ++rt)                              \
            a_[rt] = *(const f16x8*)&lds[bufi][aoff[rt]];           \
        _Pragma("unroll")                                           \
        for (int nt = 0; nt < 4; ++nt)                              \
            b_[nt] = *(const f16x8*)&lds[bufi][boff[nt]];           \
        _Pragma("unroll")                                           \
        for (int rt = 0; rt < 4; ++rt)                              \
            _Pragma("unroll")                                       \
            for (int nt = 0; nt < 4; ++nt)                          \
                acc[rt][nt] = __builtin_amdgcn_mfma_f32_16x16x32_f16( \
                    a_[rt], b_[nt], acc[rt][nt], 0, 0, 0);          \
    } while (0)

    STAGE_B(0, 0);
    __syncthreads();
    for (int ks = 0; ks < 16; ks += 2) {
        STAGE_B(1, (ks + 1) * 32);
        COMP_B(0);
        __syncthreads();
        if (ks + 2 < 16) STAGE_B(0, (ks + 2) * 32);
        COMP_B(1);
        __syncthreads();
    }
#undef STAGE_B
#undef COMP_B

    // ---- energy: partial sum over this block's 128 c -> e2[ct] slot ----
#pragma unroll
    for (int rt = 0; rt < 4; ++rt) {
        float e0 = 0.f, e1 = 0.f;
#pragma unroll
        for (int nt = 0; nt < 4; ++nt) {
            e0 += acc[rt][nt][0] * acc[rt][nt][0] + acc[rt][nt][1] * acc[rt][nt][1];
            e1 += acc[rt][nt][2] * acc[rt][nt][2] + acc[rt][nt][3] * acc[rt][nt][3];
        }
#pragma unroll
        for (int off = 1; off < 16; off <<= 1) {
            e0 += __shfl_xor(e0, off, 64);
            e1 += __shfl_xor(e1, off, 64);
        }
        if (l15 == 0) { eL[wr][wc][rt][lg][0] = e0; eL[wr][wc][rt][lg][1] = e1; }
    }
    __syncthreads();
    if (tid < 64) {
        int wr2 = tid >> 5, rt2 = (tid >> 3) & 3, lg2 = (tid >> 1) & 3, pr = tid & 1;
        int mrow = mh * 128 + wr2 * 64 + rt2 * 16 + lg2 * 4 + pr * 2;
        int f = k1 + 17 * (mrow >> 1);
        if (f < F_) {
            float e = eL[wr2][0][rt2][lg2][pr] + eL[wr2][1][rt2][lg2][pr];
            e2[(size_t)ct * (B_ * F_) + b * F_ + f] = e;
        }
    }

    // ---- X store via LDS transpose: one 256B contiguous u32-row per wave ----
    unsigned short* st = (unsigned short*)lds;     // [32][132] u16 per rt chunk
#pragma unroll
    for (int rt = 0; rt < 4; ++rt) {
        __syncthreads();
#pragma unroll
        for (int nt = 0; nt < 4; ++nt)
#pragma unroll
            for (int jj = 0; jj < 4; ++jj) {
                int ri = wr * 16 + lg * 4 + jj;
                int col = wc * 64 + nt * 16 + l15;
                st[ri * 132 + col] = f2bf(acc[rt][nt][jj]);
            }
        __syncthreads();
#pragma unroll
        for (int rr = 0; rr < 8; ++rr) {
            int ri = wid * 8 + rr;
            int mrow = mh * 128 + (ri >> 4) * 64 + rt * 16 + (ri & 15);
            int t = mrow >> 1, p = mrow & 1;
            int f = k1 + 17 * t;
            if (f < F_) {
                unsigned v = *(unsigned*)&st[ri * 132 + 2 * lane];
                *(unsigned*)(X + ((size_t)((b * F_ + f) * 2 + p)) * C_ + ct * 128 + 2 * lane) = v;
            }
        }
    }
}

// ---------------------------------------------------------------------------
// Median per batch via exact 4-pass radix select on summed energy halves.
// ---------------------------------------------------------------------------
__global__ __launch_bounds__(256) void k_median(const float* __restrict__ e2,
                                                float* __restrict__ med) {
    int b = blockIdx.x, tid = threadIdx.x;
    __shared__ unsigned vals[F_];
    __shared__ unsigned hist[256];
    __shared__ unsigned scanbuf[256];
    __shared__ unsigned sh_prefix;
    __shared__ int sh_rank;
    for (int i = tid; i < F_; i += 256)
        vals[i] = __float_as_uint(e2[b * F_ + i] + e2[(size_t)B_ * F_ + b * F_ + i]);
    if (tid == 0) { sh_prefix = 0u; sh_rank = 1024; }
    __syncthreads();
#pragma unroll
    for (int shift = 24; shift >= 0; shift -= 8) {
        hist[tid] = 0u;
        __syncthreads();
        unsigned prefix = sh_prefix;
        unsigned hmask = (shift == 24) ? 0u : (0xFFFFFFFFu << (shift + 8));
        for (int i = tid; i < F_; i += 256) {
            unsigned v = vals[i];
            if (((v ^ prefix) & hmask) == 0u)
                atomicAdd(&hist[(v >> shift) & 255], 1u);
        }
        __syncthreads();
        scanbuf[tid] = hist[tid];
        __syncthreads();
#pragma unroll
        for (int off = 1; off < 256; off <<= 1) {
            unsigned y = (tid >= off) ? scanbuf[tid - off] : 0u;
            __syncthreads();
            scanbuf[tid] += y;
            __syncthreads();
        }
        int rank = sh_rank;
        unsigned cumP = (tid == 0) ? 0u : scanbuf[tid - 1];
        unsigned cumI = scanbuf[tid];
        __syncthreads();
        if ((unsigned)rank >= cumP && (unsigned)rank < cumI) {
            sh_prefix = prefix | ((unsigned)tid << shift);
            sh_rank = rank - (int)cumP;
        }
        __syncthreads();
    }
    if (tid == 0) med[b] = __uint_as_float(sh_prefix);
}

// ---------------------------------------------------------------------------
// vbuild (tiled, 16-k2 tiles): mask + weights + inverse inner 17-point stage.
// launch_bounds(256,4): LDS 37KB x 4 = 148KB; VGPR 88 <= 128 (no spill).
// ---------------------------------------------------------------------------
__global__ __launch_bounds__(256, 4) void k_vbuild_t(
        const unsigned short* __restrict__ X, const float* __restrict__ e2,
        const float* __restrict__ med, const float* __restrict__ thr,
        const float* __restrict__ cw, const float* __restrict__ cwh,
        unsigned short* __restrict__ vt) {
    int bid = blockIdx.x;            // 32*16*8 = 4096
    int b = bid >> 7; int rem = bid & 127;
    int kt = rem >> 3, ct = rem & 7;
    int tid = threadIdx.x;
    int cl = tid & 31, ks = tid >> 5;
    int c = ct * 32 + cl;

    __shared__ unsigned stage[17 * 32 * 17];   // [m2][cl][klocal(16) pad->17] ~37KB

    float wr = cw[2 * c], wi = cw[2 * c + 1];
    float whr = cwh[2 * c], whi = cwh[2 * c + 1];
    float denom = med[b] + 1e-6f;

#pragma unroll
    for (int kk = 0; kk < 2; ++kk) {
        int klocal = kk * 8 + ks;
        int k2 = kt * 16 + klocal;
        float vr[17], vi[17];
#pragma unroll
        for (int m = 0; m < 17; ++m) { vr[m] = 0.f; vi[m] = 0.f; }
        if (k2 <= 240) {
#pragma unroll
            for (int s = 0; s < 9; ++s) {
                int f = k2 + 241 * s;
                if (f < F_) {
                    float e = e2[b * F_ + f] + e2[(size_t)B_ * F_ + b * F_ + f];
                    float m = (e / denom > thr[f]) ? 1.0f : 0.0f;
                    float wer = wr + m * whr, wei = wi + m * whi;
                    float cf = ((f == 0) ? 1.0f : 2.0f) * INV_SQRT_N;
                    const unsigned short* Xrow = X + ((size_t)(b * F_ + f) * 2) * C_;
                    float Xr = bf2f(Xrow[c]), Xi = bf2f(Xrow[C_ + c]);
                    float Zr = (Xr * wer - Xi * wei) * cf;
                    float Zi = (Xr * wei + Xi * wer) * cf;
#pragma unroll
                    for (int m2 = 0; m2 < 17; ++m2) {
                        const int r = (s * m2) % 17;
                        vr[m2] += Zr * C17T(r) - Zi * S17T(r);
                        vi[m2] += Zr * S17T(r) + Zi * C17T(r);
                    }
                }
            }
        }
#pragma unroll
        for (int m2 = 0; m2 < 17; ++m2)
            stage[(m2 * 32 + cl) * 17 + klocal] =
                (unsigned)f2bf(vr[m2]) | ((unsigned)f2bf(vi[m2]) << 16);
    }
    __syncthreads();
    unsigned* vt32 = (unsigned*)vt;
    for (int r = tid; r < 544; r += 256) {
        int m2 = r >> 5, c2 = r & 31;
        size_t ubase = ((size_t)((b * 17 + m2) * 256 + ct * 32 + c2)) * 256 + kt * 16;
        const unsigned* srow = &stage[(m2 * 32 + c2) * 17];
#pragma unroll
        for (int g = 0; g < 4; ++g) {
            uint4 w;
            w.x = srow[g * 4]; w.y = srow[g * 4 + 1];
            w.z = srow[g * 4 + 2]; w.w = srow[g * 4 + 3];
            *(uint4*)(vt32 + ubase + g * 4) = w;
        }
    }
}

// ---------------------------------------------------------------------------
// Stage C v5: double-buffered bf16 MFMA GEMM, N=256 per block (A staged once,
// 32 MFMA per 12 ds_read), LDS-transposed epilogue with full-1KB row stores.
// launch_bounds(256,2): REQUIRED — min-waves 3 forces the allocator under the
// acc[4][8] footprint and spills to scratch (R13: 85us -> 310us, WRITE x5).
// grid 1088 = B*34 (m2 x mt), chunk-swizzled; 4 waves 2Mx2N; acc[4][8].
// ---------------------------------------------------------------------------
__global__ __launch_bounds__(256, 2) void k_stageC_v5(const short* __restrict__ vt,
                                                      const short* __restrict__ twA,
                                                      float* __restrict__ out) {
    int bid = (blockIdx.x & 7) * 136 + (blockIdx.x >> 3);   // 1088 = 8*136
    int b = bid / 34, rem = bid % 34;
    int m2 = rem >> 1, mt = rem & 1;

    int tid = threadIdx.x, lane = tid & 63, wid = tid >> 6;
    int wr = wid >> 1, wc = wid & 1;
    int l15 = lane & 15, lg = lane >> 4;
    int srow = lane >> 2, sch = lane & 3;      // staging: 16 rows x 4 chunks of 16B

    const short* vtb = vt + (size_t)((b * 17 + m2) * 256) * Q_;

    // per buffer: A [128][32] (4096 sh) | B [256][32] (8192 sh) = 24 KB
    __shared__ __align__(16) short lds[2][12288];

    const short* gsrc[6];
#pragma unroll
    for (int r = 0; r < 6; ++r) {
        if (r < 2) {
            int row = r * 64 + wid * 16 + srow;            // 0..127
            int ch = sch ^ ((row >> 1) & 3);
            int n = 17 * (mt * 128 + row) + m2;
            gsrc[r] = twA + (size_t)n * Q_ + ch * 8;
        } else {
            int row = (r - 2) * 64 + wid * 16 + srow;      // 0..255
            int ch = sch ^ ((row >> 1) & 3);
            gsrc[r] = vtb + (size_t)row * Q_ + ch * 8;
        }
    }
    int aoff[4], boff[8];
#pragma unroll
    for (int rt = 0; rt < 4; ++rt) {
        int row = wr * 64 + rt * 16 + l15;
        aoff[rt] = row * 32 + (lg ^ ((row >> 1) & 3)) * 8;
    }
#pragma unroll
    for (int nt = 0; nt < 8; ++nt) {
        int row = wc * 128 + nt * 16 + l15;
        boff[nt] = 4096 + row * 32 + (lg ^ ((row >> 1) & 3)) * 8;
    }

    f32x4 acc[4][8];
#pragma unroll
    for (int rt = 0; rt < 4; ++rt)
#pragma unroll
        for (int nt = 0; nt < 8; ++nt) acc[rt][nt] = (f32x4){0.f, 0.f, 0.f, 0.f};

#define STAGE_C(bufi, q0) do {                                      \
        gload16(gsrc[0] + (q0), &lds[bufi][wid * 512]);             \
        gload16(gsrc[1] + (q0), &lds[bufi][2048 + wid * 512]);      \
        gload16(gsrc[2] + (q0), &lds[bufi][4096 + wid * 512]);      \
        gload16(gsrc[3] + (q0), &lds[bufi][6144 + wid * 512]);      \
        gload16(gsrc[4] + (q0), &lds[bufi][8192 + wid * 512]);      \
        gload16(gsrc[5] + (q0), &lds[bufi][10240 + wid * 512]);     \
    } while (0)

#define COMP_C(bufi) do {                                           \
        short8v a_[4], b_[8];                                       \
        _Pragma("unroll")                                           \
        for (int rt = 0; rt < 4; ++rt)                              \
            a_[rt] = *(const short8v*)&lds[bufi][aoff[rt]];         \
        _Pragma("unroll")                                           \
        for (int nt = 0; nt < 8; ++nt)                              \
            b_[nt] = *(const short8v*)&lds[bufi][boff[nt]];         \
        _Pragma("unroll")                                           \
        for (int rt = 0; rt < 4; ++rt)                              \
            _Pragma("unroll")                                       \
            for (int nt = 0; nt < 8; ++nt)                          \
                acc[rt][nt] = __builtin_amdgcn_mfma_f32_16x16x32_bf16( \
                    a_[rt], b_[nt], acc[rt][nt], 0, 0, 0);          \
    } while (0)

    STAGE_C(0, 0);
    __syncthreads();
    for (int ks = 0; ks < 16; ks += 2) {
        STAGE_C(1, (ks + 1) * 32);
        COMP_C(0);
        __syncthreads();
        if (ks + 2 < 16) STAGE_C(0, (ks + 2) * 32);
        COMP_C(1);
        __syncthreads();
    }
#undef STAGE_C
#undef COMP_C

    // ---- epilogue: LDS transpose -> one contiguous 1KB float4-row per wave --
    float* fl = (float*)lds;                   // [32][260] f32 per rt chunk (33 KB)
#pragma unroll
    for (int rt = 0; rt < 4; ++rt) {
        __syncthreads();
#pragma unroll
        for (int nt = 0; nt < 8; ++nt)
#pragma unroll
            for (int jj = 0; jj < 4; ++jj) {
                int ri = wr * 16 + lg * 4 + jj;
                int col = wc * 128 + nt * 16 + l15;
                fl[ri * 260 + col] = acc[rt][nt][jj];
            }
        __syncthreads();
#pragma unroll
        for (int rr = 0; rr < 8; ++rr) {
            int ri = wid * 8 + rr;
            int m1 = mt * 128 + (ri >> 4) * 64 + rt * 16 + (ri & 15);
            if (m1 < N2_) {
                int n = 17 * m1 + m2;
                float4 v = *(float4*)&fl[ri * 260 + 4 * lane];
                *(float4*)(out + ((size_t)b * N_ + n) * C_ + 4 * lane) = v;
            }
        }
    }
}

// ---------------------------------------------------------------------------
extern "C" void kernel_launch(void* const* d_in, const int* in_sizes, int n_in,
                              void* d_out, int out_size, void* d_ws, size_t ws_size,
                              hipStream_t stream) {
    const float* x   = (const float*)d_in[0];
    const float* cw  = (const float*)d_in[1];
    const float* cwh = (const float*)d_in[2];
    const float* thr = (const float*)d_in[3];
    float* out = (float*)d_out;

    // workspace (~219 MB), v_t aliases the dead y_t region:
    //   X     bf16 [B][F][2][C]          :  67,141,632
    //   SH    region (y_t | v_t):
    //     y_t  fp16 [B][9][256][512]     :  75,497,472
    //     v_t  bf16 [B][17][256][512]    : 142,606,336 (aliased at SH base)
    //   twA   bf16 [4352][512]           :   4,456,448
    //   twB   fp16 [17][256][512]        :   4,456,448
    //   e2    f32 [2][B][F]              :     524,544
    //   med   f32 [B]                    :         128
    char* ws = (char*)d_ws;
    unsigned short* Xb    = (unsigned short*)ws;
    char* sh = ws + 67141632ull;
    unsigned short* yt    = (unsigned short*)sh;
    unsigned short* vtb   = (unsigned short*)sh;                 // alias
    char* tail = sh + 142606336ull;
    unsigned short* twA   = (unsigned short*)tail;
    unsigned short* twB   = (unsigned short*)(tail + 4456448ull);
    float* e2  = (float*)(tail + 8912896ull);
    float* med = (float*)(tail + 8912896ull + 524544ull);

    k_prep<<<4224, 256, 0, stream>>>(x, yt, twA, twB);
    k_stageB_v6<<<B_ * 68, 256, 0, stream>>>(yt, twB, Xb, e2);
    k_median<<<B_, 256, 0, stream>>>(e2, med);
    k_vbuild_t<<<B_ * 128, 256, 0, stream>>>(Xb, e2, med, thr, cw, cwh, vtb);
    k_stageC_v5<<<B_ * 34, 256, 0, stream>>>((const short*)vtb, (const short*)twA, out);
}

// Round 15
// 297.073 us; speedup vs baseline: 1.8553x; 1.1187x over previous
//
#include <hip/hip_runtime.h>
#include <math.h>
#include <float.h>

#define B_ 32
#define N_ 4097
#define C_ 256
#define F_ 2049
#define N2_ 241
#define Q_ 512                        // padded K (q = 2*n2 + p, zeros q>=482)
#define TWROWS 4352                   // stageC twiddle rows (m1-tail padded)
#define INV_SQRT_N 0.0156230927f      // 1/sqrt(4097)
#define W_N 0.0015336063f             // 2*pi/4097
#define W_17 0.36959913571644626f     // 2*pi/17

typedef __attribute__((ext_vector_type(8))) short short8v;
typedef _Float16 f16x8 __attribute__((ext_vector_type(8)));
typedef __attribute__((ext_vector_type(4))) float f32x4;

// 17-point DFT twiddles as compile-time literals (cos/sin(2*pi*r/17)).
#define C17T(r) ((r)==0 ? 1.0f : (r)==1 ? 0.9324722294f : (r)==2 ? 0.7390089172f : \
    (r)==3 ? 0.4457383558f : (r)==4 ? 0.0922683595f : (r)==5 ? -0.2736629901f : \
    (r)==6 ? -0.6026346364f : (r)==7 ? -0.8502171357f : (r)==8 ? -0.9829730997f : \
    (r)==9 ? -0.9829730997f : (r)==10 ? -0.8502171357f : (r)==11 ? -0.6026346364f : \
    (r)==12 ? -0.2736629901f : (r)==13 ? 0.0922683595f : (r)==14 ? 0.4457383558f : \
    (r)==15 ? 0.7390089172f : 0.9324722294f)
#define S17T(r) ((r)==0 ? 0.0f : (r)==1 ? 0.3612416662f : (r)==2 ? 0.6736956436f : \
    (r)==3 ? 0.8951632914f : (r)==4 ? 0.9957341763f : (r)==5 ? 0.9618256432f : \
    (r)==6 ? 0.7980172273f : (r)==7 ? 0.5264321629f : (r)==8 ? 0.1837495178f : \
    (r)==9 ? -0.1837495178f : (r)==10 ? -0.5264321629f : (r)==11 ? -0.7980172273f : \
    (r)==12 ? -0.9618256432f : (r)==13 ? -0.9957341763f : (r)==14 ? -0.8951632914f : \
    (r)==15 ? -0.6736956436f : -0.3612416662f)

__device__ __forceinline__ float bf2f(unsigned short u) {
    return __uint_as_float(((unsigned)u) << 16);
}
__device__ __forceinline__ unsigned short f2bf(float v) {
    unsigned u = __float_as_uint(v);
    u += 0x7FFFu + ((u >> 16) & 1u);
    return (unsigned short)(u >> 16);
}
__device__ __forceinline__ unsigned short f2h(float v) {
    union { _Float16 h; unsigned short u; } cv;
    cv.h = (_Float16)v;               // v_cvt_f16_f32, RTN
    return cv.u;
}
__device__ __forceinline__ void gload16(const void* gptr, void* ldsptr) {
    __builtin_amdgcn_global_load_lds(
        (const __attribute__((address_space(1))) void*)gptr,
        (__attribute__((address_space(3))) void*)ldsptr,
        16, 0, 0);
}

// ---------------------------------------------------------------------------
// k_prep: fused Stage A + twiddle fills.
//  blocks [0,1952): 17-point real DFT + transpose -> y_t fp16 [b][j][c][q].
//    Thread = (c4 in [0,64), sub in [0,4)): 4 channels via FLOAT4 loads,
//    one n2 row each -> 17 vector loads/thread (was 68 scalar: VMEM-issue fix),
//    68 accumulator f32 (same as before; no spill at (256,4)).
//    XCD chunk swizzle: n2-adjacent blocks share an XCD L2 (write merging).
//  blocks [1952,4128): fill twA (bf16, stageC) and twB (fp16, stageB).
// ---------------------------------------------------------------------------
__global__ __launch_bounds__(256, 4) void k_prep(const float* __restrict__ x,
                                                 unsigned short* __restrict__ yt,
                                                 unsigned short* __restrict__ twA,
                                                 unsigned short* __restrict__ twB) {
    int blk = blockIdx.x;
    int tid = threadIdx.x;
    if (blk >= 1952) {
        int base = (blk - 1952) * 4;
#pragma unroll
        for (int u = 0; u < 4; ++u) {
            int g = base + u;
            if (g < TWROWS) {
                int n = g, k2 = tid;
                unsigned pack = 0u;
                if (n <= 4096 && k2 <= 240) {
                    int rr = (n * k2) % N_;
                    float s, cth; sincosf(W_N * (float)rr, &s, &cth);
                    pack = (unsigned)f2bf(cth) | ((unsigned)f2bf(-s) << 16);
                }
                *(unsigned*)(twA + (size_t)n * Q_ + 2 * k2) = pack;
            } else {
                int i2 = g - TWROWS;         // 0..4351
                int m = i2 & 255; int k1 = i2 >> 8;
                int n2 = tid;
                int t = m >> 1, r = m & 1;
                int f = k1 + 17 * t;
                unsigned ph = 0u;
                if (t <= 120 && f < F_ && n2 <= 240) {
                    float s_ = (k1 <= 8) ? 1.f : -1.f;
                    int rr = (f * n2) % N_;
                    float sn, cs; sincosf(W_N * (float)rr, &sn, &cs);
                    float a0 = (r == 0) ? cs : -sn;
                    float a1 = (r == 0) ? s_ * sn : s_ * cs;
                    ph = (unsigned)f2h(a0) | ((unsigned)f2h(a1) << 16);
                }
                size_t ub = ((size_t)(k1 * 256 + m)) * 256 + n2;
                *((unsigned*)twB + ub) = ph;
            }
        }
        return;
    }

    // ---- stage A path: 4 n2-rows x 256 channels per block, float4 loads ----
    int bs = (blk & 7) * 244 + (blk >> 3);   // 1952 = 8*244; n2-adjacent -> same XCD
    int b = bs / 61, n2q = bs % 61;
    int c4 = tid & 63, sub = tid >> 6;
    int n2 = n2q * 4 + sub;                  // up to 243; >240 handled as zeros
    int c = c4 * 4;
    bool valid = (n2 <= 240);

    float4 ar[9], ai[8];
#pragma unroll
    for (int k = 0; k < 9; ++k) ar[k] = make_float4(0.f, 0.f, 0.f, 0.f);
#pragma unroll
    for (int k = 0; k < 8; ++k) ai[k] = make_float4(0.f, 0.f, 0.f, 0.f);

    const float* xb = x + (size_t)b * N_ * C_ + c;
#pragma unroll
    for (int n1 = 0; n1 < 17; ++n1) {
        float4 xv = valid ? *(const float4*)(xb + (size_t)(n1 * N2_ + n2) * C_)
                          : make_float4(0.f, 0.f, 0.f, 0.f);
#pragma unroll
        for (int k1 = 0; k1 < 9; ++k1) {
            const int r = (k1 * n1) % 17;     // compile-time after unroll
            const float cc = C17T(r), ss = S17T(r);
            ar[k1].x += xv.x * cc; ar[k1].y += xv.y * cc;
            ar[k1].z += xv.z * cc; ar[k1].w += xv.w * cc;
            if (k1 > 0) {
                ai[k1 - 1].x += xv.x * ss; ai[k1 - 1].y += xv.y * ss;
                ai[k1 - 1].z += xv.z * ss; ai[k1 - 1].w += xv.w * ss;
            }
        }
    }

    __shared__ unsigned stg[3][4][260];       // 3 j-planes x 4 n2 x 256c (+pad) ~12.5KB
#pragma unroll
    for (int g = 0; g < 3; ++g) {
        __syncthreads();                      // protect previous round's reads
#pragma unroll
        for (int jj = 0; jj < 3; ++jj) {
            int j = g * 3 + jj;
            float4 re, im;
            re.x = ar[j].x * INV_SQRT_N; re.y = ar[j].y * INV_SQRT_N;
            re.z = ar[j].z * INV_SQRT_N; re.w = ar[j].w * INV_SQRT_N;
            if (j > 0) {
                im.x = -ai[j - 1].x * INV_SQRT_N; im.y = -ai[j - 1].y * INV_SQRT_N;
                im.z = -ai[j - 1].z * INV_SQRT_N; im.w = -ai[j - 1].w * INV_SQRT_N;
            } else {
                im = make_float4(0.f, 0.f, 0.f, 0.f);
            }
            uint4 p;
            p.x = (unsigned)f2h(re.x) | ((unsigned)f2h(im.x) << 16);
            p.y = (unsigned)f2h(re.y) | ((unsigned)f2h(im.y) << 16);
            p.z = (unsigned)f2h(re.z) | ((unsigned)f2h(im.z) << 16);
            p.w = (unsigned)f2h(re.w) | ((unsigned)f2h(im.w) << 16);
            *(uint4*)&stg[jj][sub][c4 * 4] = p;   // b128, stride-16B: conflict-free
        }
        __syncthreads();
#pragma unroll
        for (int jj = 0; jj < 3; ++jj) {
            int j = g * 3 + jj;
            uint4 rd;
            rd.x = stg[jj][0][tid]; rd.y = stg[jj][1][tid];
            rd.z = stg[jj][2][tid]; rd.w = stg[jj][3][tid];
            size_t ubase = ((size_t)((b * 9 + j) * 256 + tid)) * 256 + n2q * 4;
            *(uint4*)((unsigned*)yt + ubase) = rd;
        }
    }
}

// ---------------------------------------------------------------------------
// Stage B v6: double-buffered fp16 MFMA GEMM + LDS-transposed coalesced
// epilogue + atomic-free energy (e2[ct][b][f] disjoint slots, no memset).
// grid 2176 = B*68, chunk-swizzled.  (R12-verified config.)
// ---------------------------------------------------------------------------
__global__ __launch_bounds__(256) void k_stageB_v6(
        const unsigned short* __restrict__ yt, const unsigned short* __restrict__ twb,
        unsigned short* __restrict__ X, float* __restrict__ e2) {
    int bid = (blockIdx.x & 7) * 272 + (blockIdx.x >> 3);   // 2176 = 8*272
    int b = bid / 68, rem = bid % 68;
    int j, mt, ct;
    if (rem < 4) { j = 0; mt = rem >> 1; ct = rem & 1; }
    else { int r2 = rem - 4; j = 1 + (r2 >> 3); int sub = r2 & 7; mt = sub >> 1; ct = sub & 1; }
    int k1 = (mt < 2) ? j : 17 - j;
    int mh = mt & 1;
    const unsigned short* pA = twb + (size_t)(k1 * 256 + mh * 128) * Q_;
    const unsigned short* pB = yt + (size_t)((b * 9 + j) * 256 + ct * 128) * Q_;

    int tid = threadIdx.x, lane = tid & 63, wid = tid >> 6;
    int wr = wid >> 1, wc = wid & 1;
    int l15 = lane & 15, lg = lane >> 4;
    int srow = lane >> 2, sch = lane & 3;      // staging: 16 rows x 4 chunks of 16B

    __shared__ __align__(16) unsigned short lds[2][8192];  // A[128][32] | B[128][32]
    __shared__ float eL[2][2][4][4][2];

    const unsigned short* gsrc[4];
#pragma unroll
    for (int r = 0; r < 4; ++r) {
        int row = (r & 1) * 64 + wid * 16 + srow;
        int ch = sch ^ ((row >> 1) & 3);
        gsrc[r] = ((r < 2) ? pA : pB) + (size_t)row * Q_ + ch * 8;
    }
    int aoff[4], boff[4];
#pragma unroll
    for (int rt = 0; rt < 4; ++rt) {
        int row = wr * 64 + rt * 16 + l15;
        aoff[rt] = row * 32 + (lg ^ ((row >> 1) & 3)) * 8;
    }
#pragma unroll
    for (int nt = 0; nt < 4; ++nt) {
        int row = wc * 64 + nt * 16 + l15;
        boff[nt] = 4096 + row * 32 + (lg ^ ((row >> 1) & 3)) * 8;
    }

    f32x4 acc[4][4];
#pragma unroll
    for (int rt = 0; rt < 4; ++rt)
#pragma unroll
        for (int nt = 0; nt < 4; ++nt) acc[rt][nt] = (f32x4){0.f, 0.f, 0.f, 0.f};

#define STAGE_B(bufi, q0) do {                                      \
        gload16(gsrc[0] + (q0), &lds[bufi][wid * 512]);             \
        gload16(gsrc[1] + (q0), &lds[bufi][2048 + wid * 512]);      \
        gload16(gsrc[2] + (q0), &lds[bufi][4096 + wid * 512]);      \
        gload16(gsrc[3] + (q0), &lds[bufi][6144 + wid * 512]);      \
    } while (0)

#define COMP_B(bufi) do {                                           \
        f16x8 a_[4], b_[4];                                         \
        _Pragma("unroll")                                           \
        for (int rt = 0; rt < 4; ++rt)                              \
            a_[rt] = *(const f16x8*)&lds[bufi][aoff[rt]];           \
        _Pragma("unroll")                                           \
        for (int nt = 0; nt < 4; ++nt)                              \
            b_[nt] = *(const f16x8*)&lds[bufi][boff[nt]];           \
        _Pragma("unroll")                                           \
        for (int rt = 0; rt < 4; ++rt)                              \
            _Pragma("unroll")                                       \
            for (int nt = 0; nt < 4; ++nt)                          \
                acc[rt][nt] = __builtin_amdgcn_mfma_f32_16x16x32_f16( \
                    a_[rt], b_[nt], acc[rt][nt], 0, 0, 0);          \
    } while (0)

    STAGE_B(0, 0);
    __syncthreads();
    for (int ks = 0; ks < 16; ks += 2) {
        STAGE_B(1, (ks + 1) * 32);
        COMP_B(0);
        __syncthreads();
        if (ks + 2 < 16) STAGE_B(0, (ks + 2) * 32);
        COMP_B(1);
        __syncthreads();
    }
#undef STAGE_B
#undef COMP_B

    // ---- energy: partial sum over this block's 128 c -> e2[ct] slot ----
#pragma unroll
    for (int rt = 0; rt < 4; ++rt) {
        float e0 = 0.f, e1 = 0.f;
#pragma unroll
        for (int nt = 0; nt < 4; ++nt) {
            e0 += acc[rt][nt][0] * acc[rt][nt][0] + acc[rt][nt][1] * acc[rt][nt][1];
            e1 += acc[rt][nt][2] * acc[rt][nt][2] + acc[rt][nt][3] * acc[rt][nt][3];
        }
#pragma unroll
        for (int off = 1; off < 16; off <<= 1) {
            e0 += __shfl_xor(e0, off, 64);
            e1 += __shfl_xor(e1, off, 64);
        }
        if (l15 == 0) { eL[wr][wc][rt][lg][0] = e0; eL[wr][wc][rt][lg][1] = e1; }
    }
    __syncthreads();
    if (tid < 64) {
        int wr2 = tid >> 5, rt2 = (tid >> 3) & 3, lg2 = (tid >> 1) & 3, pr = tid & 1;
        int mrow = mh * 128 + wr2 * 64 + rt2 * 16 + lg2 * 4 + pr * 2;
        int f = k1 + 17 * (mrow >> 1);
        if (f < F_) {
            float e = eL[wr2][0][rt2][lg2][pr] + eL[wr2][1][rt2][lg2][pr];
            e2[(size_t)ct * (B_ * F_) + b * F_ + f] = e;
        }
    }

    // ---- X store via LDS transpose: one 256B contiguous u32-row per wave ----
    unsigned short* st = (unsigned short*)lds;     // [32][132] u16 per rt chunk
#pragma unroll
    for (int rt = 0; rt < 4; ++rt) {
        __syncthreads();
#pragma unroll
        for (int nt = 0; nt < 4; ++nt)
#pragma unroll
            for (int jj = 0; jj < 4; ++jj) {
                int ri = wr * 16 + lg * 4 + jj;
                int col = wc * 64 + nt * 16 + l15;
                st[ri * 132 + col] = f2bf(acc[rt][nt][jj]);
            }
        __syncthreads();
#pragma unroll
        for (int rr = 0; rr < 8; ++rr) {
            int ri = wid * 8 + rr;
            int mrow = mh * 128 + (ri >> 4) * 64 + rt * 16 + (ri & 15);
            int t = mrow >> 1, p = mrow & 1;
            int f = k1 + 17 * t;
            if (f < F_) {
                unsigned v = *(unsigned*)&st[ri * 132 + 2 * lane];
                *(unsigned*)(X + ((size_t)((b * F_ + f) * 2 + p)) * C_ + ct * 128 + 2 * lane) = v;
            }
        }
    }
}

// ---------------------------------------------------------------------------
// Median per batch via exact 4-pass radix select on summed energy halves.
// ---------------------------------------------------------------------------
__global__ __launch_bounds__(256) void k_median(const float* __restrict__ e2,
                                                float* __restrict__ med) {
    int b = blockIdx.x, tid = threadIdx.x;
    __shared__ unsigned vals[F_];
    __shared__ unsigned hist[256];
    __shared__ unsigned scanbuf[256];
    __shared__ unsigned sh_prefix;
    __shared__ int sh_rank;
    for (int i = tid; i < F_; i += 256)
        vals[i] = __float_as_uint(e2[b * F_ + i] + e2[(size_t)B_ * F_ + b * F_ + i]);
    if (tid == 0) { sh_prefix = 0u; sh_rank = 1024; }
    __syncthreads();
#pragma unroll
    for (int shift = 24; shift >= 0; shift -= 8) {
        hist[tid] = 0u;
        __syncthreads();
        unsigned prefix = sh_prefix;
        unsigned hmask = (shift == 24) ? 0u : (0xFFFFFFFFu << (shift + 8));
        for (int i = tid; i < F_; i += 256) {
            unsigned v = vals[i];
            if (((v ^ prefix) & hmask) == 0u)
                atomicAdd(&hist[(v >> shift) & 255], 1u);
        }
        __syncthreads();
        scanbuf[tid] = hist[tid];
        __syncthreads();
#pragma unroll
        for (int off = 1; off < 256; off <<= 1) {
            unsigned y = (tid >= off) ? scanbuf[tid - off] : 0u;
            __syncthreads();
            scanbuf[tid] += y;
            __syncthreads();
        }
        int rank = sh_rank;
        unsigned cumP = (tid == 0) ? 0u : scanbuf[tid - 1];
        unsigned cumI = scanbuf[tid];
        __syncthreads();
        if ((unsigned)rank >= cumP && (unsigned)rank < cumI) {
            sh_prefix = prefix | ((unsigned)tid << shift);
            sh_rank = rank - (int)cumP;
        }
        __syncthreads();
    }
    if (tid == 0) med[b] = __uint_as_float(sh_prefix);
}

// ---------------------------------------------------------------------------
// vbuild (tiled, 16-k2 tiles): mask + weights + inverse inner 17-point stage.
// Literal DFT tables.  Energy = sum of ct-half partials.  (R12 config.)
// ---------------------------------------------------------------------------
__global__ __launch_bounds__(256) void k_vbuild_t(
        const unsigned short* __restrict__ X, const float* __restrict__ e2,
        const float* __restrict__ med, const float* __restrict__ thr,
        const float* __restrict__ cw, const float* __restrict__ cwh,
        unsigned short* __restrict__ vt) {
    int bid = blockIdx.x;            // 32*16*8 = 4096
    int b = bid >> 7; int rem = bid & 127;
    int kt = rem >> 3, ct = rem & 7;
    int tid = threadIdx.x;
    int cl = tid & 31, ks = tid >> 5;
    int c = ct * 32 + cl;

    __shared__ unsigned stage[17 * 32 * 17];   // [m2][cl][klocal(16) pad->17] ~37KB

    float wr = cw[2 * c], wi = cw[2 * c + 1];
    float whr = cwh[2 * c], whi = cwh[2 * c + 1];
    float denom = med[b] + 1e-6f;

#pragma unroll
    for (int kk = 0; kk < 2; ++kk) {
        int klocal = kk * 8 + ks;
        int k2 = kt * 16 + klocal;
        float vr[17], vi[17];
#pragma unroll
        for (int m = 0; m < 17; ++m) { vr[m] = 0.f; vi[m] = 0.f; }
        if (k2 <= 240) {
#pragma unroll
            for (int s = 0; s < 9; ++s) {
                int f = k2 + 241 * s;
                if (f < F_) {
                    float e = e2[b * F_ + f] + e2[(size_t)B_ * F_ + b * F_ + f];
                    float m = (e / denom > thr[f]) ? 1.0f : 0.0f;
                    float wer = wr + m * whr, wei = wi + m * whi;
                    float cf = ((f == 0) ? 1.0f : 2.0f) * INV_SQRT_N;
                    const unsigned short* Xrow = X + ((size_t)(b * F_ + f) * 2) * C_;
                    float Xr = bf2f(Xrow[c]), Xi = bf2f(Xrow[C_ + c]);
                    float Zr = (Xr * wer - Xi * wei) * cf;
                    float Zi = (Xr * wei + Xi * wer) * cf;
#pragma unroll
                    for (int m2 = 0; m2 < 17; ++m2) {
                        const int r = (s * m2) % 17;
                        vr[m2] += Zr * C17T(r) - Zi * S17T(r);
                        vi[m2] += Zr * S17T(r) + Zi * C17T(r);
                    }
                }
            }
        }
#pragma unroll
        for (int m2 = 0; m2 < 17; ++m2)
            stage[(m2 * 32 + cl) * 17 + klocal] =
                (unsigned)f2bf(vr[m2]) | ((unsigned)f2bf(vi[m2]) << 16);
    }
    __syncthreads();
    unsigned* vt32 = (unsigned*)vt;
    for (int r = tid; r < 544; r += 256) {
        int m2 = r >> 5, c2 = r & 31;
        size_t ubase = ((size_t)((b * 17 + m2) * 256 + ct * 32 + c2)) * 256 + kt * 16;
        const unsigned* srow = &stage[(m2 * 32 + c2) * 17];
#pragma unroll
        for (int g = 0; g < 4; ++g) {
            uint4 w;
            w.x = srow[g * 4]; w.y = srow[g * 4 + 1];
            w.z = srow[g * 4 + 2]; w.w = srow[g * 4 + 3];
            *(uint4*)(vt32 + ubase + g * 4) = w;
        }
    }
}

// ---------------------------------------------------------------------------
// Stage C v5: double-buffered bf16 MFMA GEMM, N=256 per block (A staged once,
// 32 MFMA per 12 ds_read), LDS-transposed epilogue with full-1KB row stores.
// launch_bounds(256,2): REQUIRED — min-waves 3 forces the allocator under the
// acc[4][8] footprint and spills to scratch (R13: 85us -> 310us, WRITE x5).
// grid 1088 = B*34 (m2 x mt), chunk-swizzled; 4 waves 2Mx2N; acc[4][8].
// ---------------------------------------------------------------------------
__global__ __launch_bounds__(256, 2) void k_stageC_v5(const short* __restrict__ vt,
                                                      const short* __restrict__ twA,
                                                      float* __restrict__ out) {
    int bid = (blockIdx.x & 7) * 136 + (blockIdx.x >> 3);   // 1088 = 8*136
    int b = bid / 34, rem = bid % 34;
    int m2 = rem >> 1, mt = rem & 1;

    int tid = threadIdx.x, lane = tid & 63, wid = tid >> 6;
    int wr = wid >> 1, wc = wid & 1;
    int l15 = lane & 15, lg = lane >> 4;
    int srow = lane >> 2, sch = lane & 3;      // staging: 16 rows x 4 chunks of 16B

    const short* vtb = vt + (size_t)((b * 17 + m2) * 256) * Q_;

    // per buffer: A [128][32] (4096 sh) | B [256][32] (8192 sh) = 24 KB
    __shared__ __align__(16) short lds[2][12288];

    const short* gsrc[6];
#pragma unroll
    for (int r = 0; r < 6; ++r) {
        if (r < 2) {
            int row = r * 64 + wid * 16 + srow;            // 0..127
            int ch = sch ^ ((row >> 1) & 3);
            int n = 17 * (mt * 128 + row) + m2;
            gsrc[r] = twA + (size_t)n * Q_ + ch * 8;
        } else {
            int row = (r - 2) * 64 + wid * 16 + srow;      // 0..255
            int ch = sch ^ ((row >> 1) & 3);
            gsrc[r] = vtb + (size_t)row * Q_ + ch * 8;
        }
    }
    int aoff[4], boff[8];
#pragma unroll
    for (int rt = 0; rt < 4; ++rt) {
        int row = wr * 64 + rt * 16 + l15;
        aoff[rt] = row * 32 + (lg ^ ((row >> 1) & 3)) * 8;
    }
#pragma unroll
    for (int nt = 0; nt < 8; ++nt) {
        int row = wc * 128 + nt * 16 + l15;
        boff[nt] = 4096 + row * 32 + (lg ^ ((row >> 1) & 3)) * 8;
    }

    f32x4 acc[4][8];
#pragma unroll
    for (int rt = 0; rt < 4; ++rt)
#pragma unroll
        for (int nt = 0; nt < 8; ++nt) acc[rt][nt] = (f32x4){0.f, 0.f, 0.f, 0.f};

#define STAGE_C(bufi, q0) do {                                      \
        gload16(gsrc[0] + (q0), &lds[bufi][wid * 512]);             \
        gload16(gsrc[1] + (q0), &lds[bufi][2048 + wid * 512]);      \
        gload16(gsrc[2] + (q0), &lds[bufi][4096 + wid * 512]);      \
        gload16(gsrc[3] + (q0), &lds[bufi][6144 + wid * 512]);      \
        gload16(gsrc[4] + (q0), &lds[bufi][8192 + wid * 512]);      \
        gload16(gsrc[5] + (q0), &lds[bufi][10240 + wid * 512]);     \
    } while (0)

#define COMP_C(bufi) do {                                           \
        short8v a_[4], b_[8];                                       \
        _Pragma("unroll")                                           \
        for (int rt = 0; rt < 4; ++rt)                              \
            a_[rt] = *(const short8v*)&lds[bufi][aoff[rt]];         \
        _Pragma("unroll")                                           \
        for (int nt = 0; nt < 8; ++nt)                              \
            b_[nt] = *(const short8v*)&lds[bufi][boff[nt]];         \
        _Pragma("unroll")                                           \
        for (int rt = 0; rt < 4; ++rt)                              \
            _Pragma("unroll")                                       \
            for (int nt = 0; nt < 8; ++nt)                          \
                acc[rt][nt] = __builtin_amdgcn_mfma_f32_16x16x32_bf16( \
                    a_[rt], b_[nt], acc[rt][nt], 0, 0, 0);          \
    } while (0)

    STAGE_C(0, 0);
    __syncthreads();
    for (int ks = 0; ks < 16; ks += 2) {
        STAGE_C(1, (ks + 1) * 32);
        COMP_C(0);
        __syncthreads();
        if (ks + 2 < 16) STAGE_C(0, (ks + 2) * 32);
        COMP_C(1);
        __syncthreads();
    }
#undef STAGE_C
#undef COMP_C

    // ---- epilogue: LDS transpose -> one contiguous 1KB float4-row per wave --
    float* fl = (float*)lds;                   // [32][260] f32 per rt chunk (33 KB)
#pragma unroll
    for (int rt = 0; rt < 4; ++rt) {
        __syncthreads();
#pragma unroll
        for (int nt = 0; nt < 8; ++nt)
#pragma unroll
            for (int jj = 0; jj < 4; ++jj) {
                int ri = wr * 16 + lg * 4 + jj;
                int col = wc * 128 + nt * 16 + l15;
                fl[ri * 260 + col] = acc[rt][nt][jj];
            }
        __syncthreads();
#pragma unroll
        for (int rr = 0; rr < 8; ++rr) {
            int ri = wid * 8 + rr;
            int m1 = mt * 128 + (ri >> 4) * 64 + rt * 16 + (ri & 15);
            if (m1 < N2_) {
                int n = 17 * m1 + m2;
                float4 v = *(float4*)&fl[ri * 260 + 4 * lane];
                *(float4*)(out + ((size_t)b * N_ + n) * C_ + 4 * lane) = v;
            }
        }
    }
}

// ---------------------------------------------------------------------------
extern "C" void kernel_launch(void* const* d_in, const int* in_sizes, int n_in,
                              void* d_out, int out_size, void* d_ws, size_t ws_size,
                              hipStream_t stream) {
    const float* x   = (const float*)d_in[0];
    const float* cw  = (const float*)d_in[1];
    const float* cwh = (const float*)d_in[2];
    const float* thr = (const float*)d_in[3];
    float* out = (float*)d_out;

    // workspace (~219 MB), v_t aliases the dead y_t region:
    //   X     bf16 [B][F][2][C]          :  67,141,632
    //   SH    region (y_t | v_t):
    //     y_t  fp16 [B][9][256][512]     :  75,497,472
    //     v_t  bf16 [B][17][256][512]    : 142,606,336 (aliased at SH base)
    //   twA   bf16 [4352][512]           :   4,456,448
    //   twB   fp16 [17][256][512]        :   4,456,448
    //   e2    f32 [2][B][F]              :     524,544
    //   med   f32 [B]                    :         128
    char* ws = (char*)d_ws;
    unsigned short* Xb    = (unsigned short*)ws;
    char* sh = ws + 67141632ull;
    unsigned short* yt    = (unsigned short*)sh;
    unsigned short* vtb   = (unsigned short*)sh;                 // alias
    char* tail = sh + 142606336ull;
    unsigned short* twA   = (unsigned short*)tail;
    unsigned short* twB   = (unsigned short*)(tail + 4456448ull);
    float* e2  = (float*)(tail + 8912896ull);
    float* med = (float*)(tail + 8912896ull + 524544ull);

    k_prep<<<4128, 256, 0, stream>>>(x, yt, twA, twB);
    k_stageB_v6<<<B_ * 68, 256, 0, stream>>>(yt, twB, Xb, e2);
    k_median<<<B_, 256, 0, stream>>>(e2, med);
    k_vbuild_t<<<B_ * 128, 256, 0, stream>>>(Xb, e2, med, thr, cw, cwh, vtb);
    k_stageC_v5<<<B_ * 34, 256, 0, stream>>>((const short*)vtb, (const short*)twA, out);
}

// Round 17
// 282.452 us; speedup vs baseline: 1.9513x; 1.0518x over previous
//
#include <hip/hip_runtime.h>
#include <math.h>
#include <float.h>

#define B_ 32
#define N_ 4097
#define C_ 256
#define F_ 2049
#define N2_ 241
#define Q_ 512                        // padded K (q = 2*n2 + p, zeros q>=482)
#define TWROWS 4352                   // stageC twiddle rows (m1-tail padded)
#define INV_SQRT_N 0.0156230927f      // 1/sqrt(4097)
#define W_N 0.0015336063f             // 2*pi/4097
#define W_17 0.36959913571644626f     // 2*pi/17

typedef __attribute__((ext_vector_type(8))) short short8v;
typedef _Float16 f16x8 __attribute__((ext_vector_type(8)));
typedef __attribute__((ext_vector_type(4))) float f32x4;

// 17-point DFT twiddles as compile-time literals (cos/sin(2*pi*r/17)).
#define C17T(r) ((r)==0 ? 1.0f : (r)==1 ? 0.9324722294f : (r)==2 ? 0.7390089172f : \
    (r)==3 ? 0.4457383558f : (r)==4 ? 0.0922683595f : (r)==5 ? -0.2736629901f : \
    (r)==6 ? -0.6026346364f : (r)==7 ? -0.8502171357f : (r)==8 ? -0.9829730997f : \
    (r)==9 ? -0.9829730997f : (r)==10 ? -0.8502171357f : (r)==11 ? -0.6026346364f : \
    (r)==12 ? -0.2736629901f : (r)==13 ? 0.0922683595f : (r)==14 ? 0.4457383558f : \
    (r)==15 ? 0.7390089172f : 0.9324722294f)
#define S17T(r) ((r)==0 ? 0.0f : (r)==1 ? 0.3612416662f : (r)==2 ? 0.6736956436f : \
    (r)==3 ? 0.8951632914f : (r)==4 ? 0.9957341763f : (r)==5 ? 0.9618256432f : \
    (r)==6 ? 0.7980172273f : (r)==7 ? 0.5264321629f : (r)==8 ? 0.1837495178f : \
    (r)==9 ? -0.1837495178f : (r)==10 ? -0.5264321629f : (r)==11 ? -0.7980172273f : \
    (r)==12 ? -0.9618256432f : (r)==13 ? -0.9957341763f : (r)==14 ? -0.8951632914f : \
    (r)==15 ? -0.6736956436f : -0.3612416662f)

__device__ __forceinline__ float bf2f(unsigned short u) {
    return __uint_as_float(((unsigned)u) << 16);
}
__device__ __forceinline__ unsigned short f2bf(float v) {
    unsigned u = __float_as_uint(v);
    u += 0x7FFFu + ((u >> 16) & 1u);
    return (unsigned short)(u >> 16);
}
__device__ __forceinline__ unsigned short f2h(float v) {
    union { _Float16 h; unsigned short u; } cv;
    cv.h = (_Float16)v;               // v_cvt_f16_f32, RTN
    return cv.u;
}
__device__ __forceinline__ void gload16(const void* gptr, void* ldsptr) {
    __builtin_amdgcn_global_load_lds(
        (const __attribute__((address_space(1))) void*)gptr,
        (__attribute__((address_space(3))) void*)ldsptr,
        16, 0, 0);
}

// ---------------------------------------------------------------------------
// k_prep: fused Stage A + twiddle fills.
//  blocks [0,2048): 17-point real DFT + transpose -> y_t fp16 [b][j][c][q].
//    Block = (b, 16-n2 tile, 64-channel tile); thread = (c4, sub): 4 channels
//    via float4 loads (17/thread), 1 n2 row.  Per j-plane the block owns a
//    FULL 64B line per channel row -> uint4 stores with chunk-fast lane order.
//    NOTE: stageA has exactly 9 j-planes (j=0..8) — 3 LDS rounds of 3
//    (R16 bug: looped to j=16, reading past ar[9] and writing past the slice).
//  blocks [2048,4224): fill twA (bf16, stageC) and twB (fp16, stageB).
// ---------------------------------------------------------------------------
__global__ __launch_bounds__(256) void k_prep(const float* __restrict__ x,
                                              unsigned short* __restrict__ yt,
                                              unsigned short* __restrict__ twA,
                                              unsigned short* __restrict__ twB) {
    int blk = blockIdx.x;
    int tid = threadIdx.x;
    if (blk >= 2048) {
        int base = (blk - 2048) * 4;
#pragma unroll
        for (int u = 0; u < 4; ++u) {
            int g = base + u;
            if (g < TWROWS) {
                int n = g, k2 = tid;
                unsigned pack = 0u;
                if (n <= 4096 && k2 <= 240) {
                    int rr = (n * k2) % N_;
                    float s, cth; sincosf(W_N * (float)rr, &s, &cth);
                    pack = (unsigned)f2bf(cth) | ((unsigned)f2bf(-s) << 16);
                }
                *(unsigned*)(twA + (size_t)n * Q_ + 2 * k2) = pack;
            } else {
                int i2 = g - TWROWS;         // 0..4351
                int m = i2 & 255; int k1 = i2 >> 8;
                int n2 = tid;
                int t = m >> 1, r = m & 1;
                int f = k1 + 17 * t;
                unsigned ph = 0u;
                if (t <= 120 && f < F_ && n2 <= 240) {
                    float s_ = (k1 <= 8) ? 1.f : -1.f;
                    int rr = (f * n2) % N_;
                    float sn, cs; sincosf(W_N * (float)rr, &sn, &cs);
                    float a0 = (r == 0) ? cs : -sn;
                    float a1 = (r == 0) ? s_ * sn : s_ * cs;
                    ph = (unsigned)f2h(a0) | ((unsigned)f2h(a1) << 16);
                }
                size_t ub = ((size_t)(k1 * 256 + m)) * 256 + n2;
                *((unsigned*)twB + ub) = ph;
            }
        }
        return;
    }

    // ---- stage A path: 16 n2-rows x 64 channels per block ----
    int b = blk >> 6; int rem = blk & 63;
    int n2t = rem >> 2, ct = rem & 3;
    int c4 = tid & 15, sub = tid >> 4;
    int n2 = n2t * 16 + sub;                 // up to 255; >240 handled as zeros
    int c = ct * 64 + c4 * 4;
    bool valid = (n2 <= 240);

    float4 ar[9], ai[8];
#pragma unroll
    for (int k = 0; k < 9; ++k) ar[k] = make_float4(0.f, 0.f, 0.f, 0.f);
#pragma unroll
    for (int k = 0; k < 8; ++k) ai[k] = make_float4(0.f, 0.f, 0.f, 0.f);

    const float* xb = x + (size_t)b * N_ * C_ + c;
#pragma unroll
    for (int n1 = 0; n1 < 17; ++n1) {
        float4 xv = valid ? *(const float4*)(xb + (size_t)(n1 * N2_ + n2) * C_)
                          : make_float4(0.f, 0.f, 0.f, 0.f);
#pragma unroll
        for (int k1 = 0; k1 < 9; ++k1) {
            const int r = (k1 * n1) % 17;     // compile-time after unroll
            const float cc = C17T(r), ss = S17T(r);
            ar[k1].x += xv.x * cc; ar[k1].y += xv.y * cc;
            ar[k1].z += xv.z * cc; ar[k1].w += xv.w * cc;
            if (k1 > 0) {
                ai[k1 - 1].x += xv.x * ss; ai[k1 - 1].y += xv.y * ss;
                ai[k1 - 1].z += xv.z * ss; ai[k1 - 1].w += xv.w * ss;
            }
        }
    }

    __shared__ unsigned stg[3][16][68];       // [jj][n2local][c(64)+pad] ~12.75KB
    int c_row = tid >> 2, chunk = tid & 3;
#pragma unroll
    for (int g = 0; g < 3; ++g) {
        __syncthreads();                      // protect previous round's reads
#pragma unroll
        for (int jj = 0; jj < 3; ++jj) {
            int j = g * 3 + jj;               // 0..8 exactly (9 planes)
            float4 re, im;
            re.x = ar[j].x * INV_SQRT_N; re.y = ar[j].y * INV_SQRT_N;
            re.z = ar[j].z * INV_SQRT_N; re.w = ar[j].w * INV_SQRT_N;
            if (j > 0) {
                im.x = -ai[j - 1].x * INV_SQRT_N; im.y = -ai[j - 1].y * INV_SQRT_N;
                im.z = -ai[j - 1].z * INV_SQRT_N; im.w = -ai[j - 1].w * INV_SQRT_N;
            } else {
                im = make_float4(0.f, 0.f, 0.f, 0.f);
            }
            uint4 p;
            p.x = (unsigned)f2h(re.x) | ((unsigned)f2h(im.x) << 16);
            p.y = (unsigned)f2h(re.y) | ((unsigned)f2h(im.y) << 16);
            p.z = (unsigned)f2h(re.z) | ((unsigned)f2h(im.z) << 16);
            p.w = (unsigned)f2h(re.w) | ((unsigned)f2h(im.w) << 16);
            *(uint4*)&stg[jj][sub][c4 * 4] = p;
        }
        __syncthreads();
#pragma unroll
        for (int jj = 0; jj < 3; ++jj) {
            int j = g * 3 + jj;
            uint4 rd;
            rd.x = stg[jj][chunk * 4 + 0][c_row];
            rd.y = stg[jj][chunk * 4 + 1][c_row];
            rd.z = stg[jj][chunk * 4 + 2][c_row];
            rd.w = stg[jj][chunk * 4 + 3][c_row];
            size_t ubase = ((size_t)((b * 9 + j) * 256 + ct * 64 + c_row)) * 256
                           + n2t * 16 + chunk * 4;
            *(uint4*)((unsigned*)yt + ubase) = rd;
        }
    }
}

// ---------------------------------------------------------------------------
// Stage B v6: double-buffered fp16 MFMA GEMM + LDS-transposed coalesced
// epilogue + atomic-free energy (e2[ct][b][f] disjoint slots, no memset).
// grid 2176 = B*68, chunk-swizzled.  (R12-verified config.)
// ---------------------------------------------------------------------------
__global__ __launch_bounds__(256) void k_stageB_v6(
        const unsigned short* __restrict__ yt, const unsigned short* __restrict__ twb,
        unsigned short* __restrict__ X, float* __restrict__ e2) {
    int bid = (blockIdx.x & 7) * 272 + (blockIdx.x >> 3);   // 2176 = 8*272
    int b = bid / 68, rem = bid % 68;
    int j, mt, ct;
    if (rem < 4) { j = 0; mt = rem >> 1; ct = rem & 1; }
    else { int r2 = rem - 4; j = 1 + (r2 >> 3); int sub = r2 & 7; mt = sub >> 1; ct = sub & 1; }
    int k1 = (mt < 2) ? j : 17 - j;
    int mh = mt & 1;
    const unsigned short* pA = twb + (size_t)(k1 * 256 + mh * 128) * Q_;
    const unsigned short* pB = yt + (size_t)((b * 9 + j) * 256 + ct * 128) * Q_;

    int tid = threadIdx.x, lane = tid & 63, wid = tid >> 6;
    int wr = wid >> 1, wc = wid & 1;
    int l15 = lane & 15, lg = lane >> 4;
    int srow = lane >> 2, sch = lane & 3;      // staging: 16 rows x 4 chunks of 16B

    __shared__ __align__(16) unsigned short lds[2][8192];  // A[128][32] | B[128][32]
    __shared__ float eL[2][2][4][4][2];

    const unsigned short* gsrc[4];
#pragma unroll
    for (int r = 0; r < 4; ++r) {
        int row = (r & 1) * 64 + wid * 16 + srow;
        int ch = sch ^ ((row >> 1) & 3);
        gsrc[r] = ((r < 2) ? pA : pB) + (size_t)row * Q_ + ch * 8;
    }
    int aoff[4], boff[4];
#pragma unroll
    for (int rt = 0; rt < 4; ++rt) {
        int row = wr * 64 + rt * 16 + l15;
        aoff[rt] = row * 32 + (lg ^ ((row >> 1) & 3)) * 8;
    }
#pragma unroll
    for (int nt = 0; nt < 4; ++nt) {
        int row = wc * 64 + nt * 16 + l15;
        boff[nt] = 4096 + row * 32 + (lg ^ ((row >> 1) & 3)) * 8;
    }

    f32x4 acc[4][4];
#pragma unroll
    for (int rt = 0; rt < 4; ++rt)
#pragma unroll
        for (int nt = 0; nt < 4; ++nt) acc[rt][nt] = (f32x4){0.f, 0.f, 0.f, 0.f};

#define STAGE_B(bufi, q0) do {                                      \
        gload16(gsrc[0] + (q0), &lds[bufi][wid * 512]);             \
        gload16(gsrc[1] + (q0), &lds[bufi][2048 + wid * 512]);      \
        gload16(gsrc[2] + (q0), &lds[bufi][4096 + wid * 512]);      \
        gload16(gsrc[3] + (q0), &lds[bufi][6144 + wid * 512]);      \
    } while (0)

#define COMP_B(bufi) do {                                           \
        f16x8 a_[4], b_[4];                                         \
        _Pragma("unroll")                                           \
        for (int rt = 0; rt < 4; ++rt)                              \
            a_[rt] = *(const f16x8*)&lds[bufi][aoff[rt]];           \
        _Pragma("unroll")                                           \
        for (int nt = 0; nt < 4; ++nt)                              \
            b_[nt] = *(const f16x8*)&lds[bufi][boff[nt]];           \
        _Pragma("unroll")                                           \
        for (int rt = 0; rt < 4; ++rt)                              \
            _Pragma("unroll")                                       \
            for (int nt = 0; nt < 4; ++nt)                          \
                acc[rt][nt] = __builtin_amdgcn_mfma_f32_16x16x32_f16( \
                    a_[rt], b_[nt], acc[rt][nt], 0, 0, 0);          \
    } while (0)

    STAGE_B(0, 0);
    __syncthreads();
    for (int ks = 0; ks < 16; ks += 2) {
        STAGE_B(1, (ks + 1) * 32);
        COMP_B(0);
        __syncthreads();
        if (ks + 2 < 16) STAGE_B(0, (ks + 2) * 32);
        COMP_B(1);
        __syncthreads();
    }
#undef STAGE_B
#undef COMP_B

    // ---- energy: partial sum over this block's 128 c -> e2[ct] slot ----
#pragma unroll
    for (int rt = 0; rt < 4; ++rt) {
        float e0 = 0.f, e1 = 0.f;
#pragma unroll
        for (int nt = 0; nt < 4; ++nt) {
            e0 += acc[rt][nt][0] * acc[rt][nt][0] + acc[rt][nt][1] * acc[rt][nt][1];
            e1 += acc[rt][nt][2] * acc[rt][nt][2] + acc[rt][nt][3] * acc[rt][nt][3];
        }
#pragma unroll
        for (int off = 1; off < 16; off <<= 1) {
            e0 += __shfl_xor(e0, off, 64);
            e1 += __shfl_xor(e1, off, 64);
        }
        if (l15 == 0) { eL[wr][wc][rt][lg][0] = e0; eL[wr][wc][rt][lg][1] = e1; }
    }
    __syncthreads();
    if (tid < 64) {
        int wr2 = tid >> 5, rt2 = (tid >> 3) & 3, lg2 = (tid >> 1) & 3, pr = tid & 1;
        int mrow = mh * 128 + wr2 * 64 + rt2 * 16 + lg2 * 4 + pr * 2;
        int f = k1 + 17 * (mrow >> 1);
        if (f < F_) {
            float e = eL[wr2][0][rt2][lg2][pr] + eL[wr2][1][rt2][lg2][pr];
            e2[(size_t)ct * (B_ * F_) + b * F_ + f] = e;
        }
    }

    // ---- X store via LDS transpose: one 256B contiguous u32-row per wave ----
    unsigned short* st = (unsigned short*)lds;     // [32][132] u16 per rt chunk
#pragma unroll
    for (int rt = 0; rt < 4; ++rt) {
        __syncthreads();
#pragma unroll
        for (int nt = 0; nt < 4; ++nt)
#pragma unroll
            for (int jj = 0; jj < 4; ++jj) {
                int ri = wr * 16 + lg * 4 + jj;
                int col = wc * 64 + nt * 16 + l15;
                st[ri * 132 + col] = f2bf(acc[rt][nt][jj]);
            }
        __syncthreads();
#pragma unroll
        for (int rr = 0; rr < 8; ++rr) {
            int ri = wid * 8 + rr;
            int mrow = mh * 128 + (ri >> 4) * 64 + rt * 16 + (ri & 15);
            int t = mrow >> 1, p = mrow & 1;
            int f = k1 + 17 * t;
            if (f < F_) {
                unsigned v = *(unsigned*)&st[ri * 132 + 2 * lane];
                *(unsigned*)(X + ((size_t)((b * F_ + f) * 2 + p)) * C_ + ct * 128 + 2 * lane) = v;
            }
        }
    }
}

// ---------------------------------------------------------------------------
// Median per batch via exact 4-pass radix select on summed energy halves.
// ---------------------------------------------------------------------------
__global__ __launch_bounds__(256) void k_median(const float* __restrict__ e2,
                                                float* __restrict__ med) {
    int b = blockIdx.x, tid = threadIdx.x;
    __shared__ unsigned vals[F_];
    __shared__ unsigned hist[256];
    __shared__ unsigned scanbuf[256];
    __shared__ unsigned sh_prefix;
    __shared__ int sh_rank;
    for (int i = tid; i < F_; i += 256)
        vals[i] = __float_as_uint(e2[b * F_ + i] + e2[(size_t)B_ * F_ + b * F_ + i]);
    if (tid == 0) { sh_prefix = 0u; sh_rank = 1024; }
    __syncthreads();
#pragma unroll
    for (int shift = 24; shift >= 0; shift -= 8) {
        hist[tid] = 0u;
        __syncthreads();
        unsigned prefix = sh_prefix;
        unsigned hmask = (shift == 24) ? 0u : (0xFFFFFFFFu << (shift + 8));
        for (int i = tid; i < F_; i += 256) {
            unsigned v = vals[i];
            if (((v ^ prefix) & hmask) == 0u)
                atomicAdd(&hist[(v >> shift) & 255], 1u);
        }
        __syncthreads();
        scanbuf[tid] = hist[tid];
        __syncthreads();
#pragma unroll
        for (int off = 1; off < 256; off <<= 1) {
            unsigned y = (tid >= off) ? scanbuf[tid - off] : 0u;
            __syncthreads();
            scanbuf[tid] += y;
            __syncthreads();
        }
        int rank = sh_rank;
        unsigned cumP = (tid == 0) ? 0u : scanbuf[tid - 1];
        unsigned cumI = scanbuf[tid];
        __syncthreads();
        if ((unsigned)rank >= cumP && (unsigned)rank < cumI) {
            sh_prefix = prefix | ((unsigned)tid << shift);
            sh_rank = rank - (int)cumP;
        }
        __syncthreads();
    }
    if (tid == 0) med[b] = __uint_as_float(sh_prefix);
}

// ---------------------------------------------------------------------------
// vbuild (tiled, 16-k2 tiles): mask + weights + inverse inner 17-point stage.
// Literal DFT tables.  Energy = sum of ct-half partials.  (R12 config.)
// ---------------------------------------------------------------------------
__global__ __launch_bounds__(256) void k_vbuild_t(
        const unsigned short* __restrict__ X, const float* __restrict__ e2,
        const float* __restrict__ med, const float* __restrict__ thr,
        const float* __restrict__ cw, const float* __restrict__ cwh,
        unsigned short* __restrict__ vt) {
    int bid = blockIdx.x;            // 32*16*8 = 4096
    int b = bid >> 7; int rem = bid & 127;
    int kt = rem >> 3, ct = rem & 7;
    int tid = threadIdx.x;
    int cl = tid & 31, ks = tid >> 5;
    int c = ct * 32 + cl;

    __shared__ unsigned stage[17 * 32 * 17];   // [m2][cl][klocal(16) pad->17] ~37KB

    float wr = cw[2 * c], wi = cw[2 * c + 1];
    float whr = cwh[2 * c], whi = cwh[2 * c + 1];
    float denom = med[b] + 1e-6f;

#pragma unroll
    for (int kk = 0; kk < 2; ++kk) {
        int klocal = kk * 8 + ks;
        int k2 = kt * 16 + klocal;
        float vr[17], vi[17];
#pragma unroll
        for (int m = 0; m < 17; ++m) { vr[m] = 0.f; vi[m] = 0.f; }
        if (k2 <= 240) {
#pragma unroll
            for (int s = 0; s < 9; ++s) {
                int f = k2 + 241 * s;
                if (f < F_) {
                    float e = e2[b * F_ + f] + e2[(size_t)B_ * F_ + b * F_ + f];
                    float m = (e / denom > thr[f]) ? 1.0f : 0.0f;
                    float wer = wr + m * whr, wei = wi + m * whi;
                    float cf = ((f == 0) ? 1.0f : 2.0f) * INV_SQRT_N;
                    const unsigned short* Xrow = X + ((size_t)(b * F_ + f) * 2) * C_;
                    float Xr = bf2f(Xrow[c]), Xi = bf2f(Xrow[C_ + c]);
                    float Zr = (Xr * wer - Xi * wei) * cf;
                    float Zi = (Xr * wei + Xi * wer) * cf;
#pragma unroll
                    for (int m2 = 0; m2 < 17; ++m2) {
                        const int r = (s * m2) % 17;
                        vr[m2] += Zr * C17T(r) - Zi * S17T(r);
                        vi[m2] += Zr * S17T(r) + Zi * C17T(r);
                    }
                }
            }
        }
#pragma unroll
        for (int m2 = 0; m2 < 17; ++m2)
            stage[(m2 * 32 + cl) * 17 + klocal] =
                (unsigned)f2bf(vr[m2]) | ((unsigned)f2bf(vi[m2]) << 16);
    }
    __syncthreads();
    unsigned* vt32 = (unsigned*)vt;
    for (int r = tid; r < 544; r += 256) {
        int m2 = r >> 5, c2 = r & 31;
        size_t ubase = ((size_t)((b * 17 + m2) * 256 + ct * 32 + c2)) * 256 + kt * 16;
        const unsigned* srow = &stage[(m2 * 32 + c2) * 17];
#pragma unroll
        for (int g = 0; g < 4; ++g) {
            uint4 w;
            w.x = srow[g * 4]; w.y = srow[g * 4 + 1];
            w.z = srow[g * 4 + 2]; w.w = srow[g * 4 + 3];
            *(uint4*)(vt32 + ubase + g * 4) = w;
        }
    }
}

// ---------------------------------------------------------------------------
// Stage C v5: double-buffered bf16 MFMA GEMM, N=256 per block (A staged once,
// 32 MFMA per 12 ds_read), LDS-transposed epilogue with full-1KB row stores.
// launch_bounds(256,2): REQUIRED — min-waves 3 forces the allocator under the
// acc[4][8] footprint and spills to scratch (R13: 85us -> 310us, WRITE x5).
// grid 1088 = B*34 (m2 x mt), chunk-swizzled; 4 waves 2Mx2N; acc[4][8].
// ---------------------------------------------------------------------------
__global__ __launch_bounds__(256, 2) void k_stageC_v5(const short* __restrict__ vt,
                                                      const short* __restrict__ twA,
                                                      float* __restrict__ out) {
    int bid = (blockIdx.x & 7) * 136 + (blockIdx.x >> 3);   // 1088 = 8*136
    int b = bid / 34, rem = bid % 34;
    int m2 = rem >> 1, mt = rem & 1;

    int tid = threadIdx.x, lane = tid & 63, wid = tid >> 6;
    int wr = wid >> 1, wc = wid & 1;
    int l15 = lane & 15, lg = lane >> 4;
    int srow = lane >> 2, sch = lane & 3;      // staging: 16 rows x 4 chunks of 16B

    const short* vtb = vt + (size_t)((b * 17 + m2) * 256) * Q_;

    // per buffer: A [128][32] (4096 sh) | B [256][32] (8192 sh) = 24 KB
    __shared__ __align__(16) short lds[2][12288];

    const short* gsrc[6];
#pragma unroll
    for (int r = 0; r < 6; ++r) {
        if (r < 2) {
            int row = r * 64 + wid * 16 + srow;            // 0..127
            int ch = sch ^ ((row >> 1) & 3);
            int n = 17 * (mt * 128 + row) + m2;
            gsrc[r] = twA + (size_t)n * Q_ + ch * 8;
        } else {
            int row = (r - 2) * 64 + wid * 16 + srow;      // 0..255
            int ch = sch ^ ((row >> 1) & 3);
            gsrc[r] = vtb + (size_t)row * Q_ + ch * 8;
        }
    }
    int aoff[4], boff[8];
#pragma unroll
    for (int rt = 0; rt < 4; ++rt) {
        int row = wr * 64 + rt * 16 + l15;
        aoff[rt] = row * 32 + (lg ^ ((row >> 1) & 3)) * 8;
    }
#pragma unroll
    for (int nt = 0; nt < 8; ++nt) {
        int row = wc * 128 + nt * 16 + l15;
        boff[nt] = 4096 + row * 32 + (lg ^ ((row >> 1) & 3)) * 8;
    }

    f32x4 acc[4][8];
#pragma unroll
    for (int rt = 0; rt < 4; ++rt)
#pragma unroll
        for (int nt = 0; nt < 8; ++nt) acc[rt][nt] = (f32x4){0.f, 0.f, 0.f, 0.f};

#define STAGE_C(bufi, q0) do {                                      \
        gload16(gsrc[0] + (q0), &lds[bufi][wid * 512]);             \
        gload16(gsrc[1] + (q0), &lds[bufi][2048 + wid * 512]);      \
        gload16(gsrc[2] + (q0), &lds[bufi][4096 + wid * 512]);      \
        gload16(gsrc[3] + (q0), &lds[bufi][6144 + wid * 512]);      \
        gload16(gsrc[4] + (q0), &lds[bufi][8192 + wid * 512]);      \
        gload16(gsrc[5] + (q0), &lds[bufi][10240 + wid * 512]);     \
    } while (0)

#define COMP_C(bufi) do {                                           \
        short8v a_[4], b_[8];                                       \
        _Pragma("unroll")                                           \
        for (int rt = 0; rt < 4; ++rt)                              \
            a_[rt] = *(const short8v*)&lds[bufi][aoff[rt]];         \
        _Pragma("unroll")                                           \
        for (int nt = 0; nt < 8; ++nt)                              \
            b_[nt] = *(const short8v*)&lds[bufi][boff[nt]];         \
        _Pragma("unroll")                                           \
        for (int rt = 0; rt < 4; ++rt)                              \
            _Pragma("unroll")                                       \
            for (int nt = 0; nt < 8; ++nt)                          \
                acc[rt][nt] = __builtin_amdgcn_mfma_f32_16x16x32_bf16( \
                    a_[rt], b_[nt], acc[rt][nt], 0, 0, 0);          \
    } while (0)

    STAGE_C(0, 0);
    __syncthreads();
    for (int ks = 0; ks < 16; ks += 2) {
        STAGE_C(1, (ks + 1) * 32);
        COMP_C(0);
        __syncthreads();
        if (ks + 2 < 16) STAGE_C(0, (ks + 2) * 32);
        COMP_C(1);
        __syncthreads();
    }
#undef STAGE_C
#undef COMP_C

    // ---- epilogue: LDS transpose -> one contiguous 1KB float4-row per wave --
    float* fl = (float*)lds;                   // [32][260] f32 per rt chunk (33 KB)
#pragma unroll
    for (int rt = 0; rt < 4; ++rt) {
        __syncthreads();
#pragma unroll
        for (int nt = 0; nt < 8; ++nt)
#pragma unroll
            for (int jj = 0; jj < 4; ++jj) {
                int ri = wr * 16 + lg * 4 + jj;
                int col = wc * 128 + nt * 16 + l15;
                fl[ri * 260 + col] = acc[rt][nt][jj];
            }
        __syncthreads();
#pragma unroll
        for (int rr = 0; rr < 8; ++rr) {
            int ri = wid * 8 + rr;
            int m1 = mt * 128 + (ri >> 4) * 64 + rt * 16 + (ri & 15);
            if (m1 < N2_) {
                int n = 17 * m1 + m2;
                float4 v = *(float4*)&fl[ri * 260 + 4 * lane];
                *(float4*)(out + ((size_t)b * N_ + n) * C_ + 4 * lane) = v;
            }
        }
    }
}

// ---------------------------------------------------------------------------
extern "C" void kernel_launch(void* const* d_in, const int* in_sizes, int n_in,
                              void* d_out, int out_size, void* d_ws, size_t ws_size,
                              hipStream_t stream) {
    const float* x   = (const float*)d_in[0];
    const float* cw  = (const float*)d_in[1];
    const float* cwh = (const float*)d_in[2];
    const float* thr = (const float*)d_in[3];
    float* out = (float*)d_out;

    // workspace (~219 MB), v_t aliases the dead y_t region:
    //   X     bf16 [B][F][2][C]          :  67,141,632
    //   SH    region (y_t | v_t):
    //     y_t  fp16 [B][9][256][512]     :  75,497,472
    //     v_t  bf16 [B][17][256][512]    : 142,606,336 (aliased at SH base)
    //   twA   bf16 [4352][512]           :   4,456,448
    //   twB   fp16 [17][256][512]        :   4,456,448
    //   e2    f32 [2][B][F]              :     524,544
    //   med   f32 [B]                    :         128
    char* ws = (char*)d_ws;
    unsigned short* Xb    = (unsigned short*)ws;
    char* sh = ws + 67141632ull;
    unsigned short* yt    = (unsigned short*)sh;
    unsigned short* vtb   = (unsigned short*)sh;                 // alias
    char* tail = sh + 142606336ull;
    unsigned short* twA   = (unsigned short*)tail;
    unsigned short* twB   = (unsigned short*)(tail + 4456448ull);
    float* e2  = (float*)(tail + 8912896ull);
    float* med = (float*)(tail + 8912896ull + 524544ull);

    k_prep<<<4224, 256, 0, stream>>>(x, yt, twA, twB);
    k_stageB_v6<<<B_ * 68, 256, 0, stream>>>(yt, twB, Xb, e2);
    k_median<<<B_, 256, 0, stream>>>(e2, med);
    k_vbuild_t<<<B_ * 128, 256, 0, stream>>>(Xb, e2, med, thr, cw, cwh, vtb);
    k_stageC_v5<<<B_ * 34, 256, 0, stream>>>((const short*)vtb, (const short*)twA, out);
}